// Round 1
// baseline (1265.913 us; speedup 1.0000x reference)
//
#include <hip/hip_runtime.h>

typedef __bf16 bf16x8 __attribute__((ext_vector_type(8)));
typedef float f32x4 __attribute__((ext_vector_type(4)));

__device__ __forceinline__ unsigned short f2bf(float f) {
  unsigned u = __builtin_bit_cast(unsigned, f);
  u += 0x7fffu + ((u >> 16) & 1u);
  return (unsigned short)(u >> 16);
}
__device__ __forceinline__ float bf2f(unsigned short h) {
  unsigned u = ((unsigned)h) << 16;
  return __builtin_bit_cast(float, u);
}
__device__ __forceinline__ void gload16(const void* g, void* l) {
  __builtin_amdgcn_global_load_lds((const __attribute__((address_space(1))) void*)g,
                                   (__attribute__((address_space(3))) void*)l, 16, 0, 0);
}

// ---------------- phase A: means / queries / attention / ets ----------------

// qs_pre[b,n,q] = (mean_t x[b,n,:,:]) @ W_Q0
__global__ __launch_bounds__(256) void k_qs_pre(const float* __restrict__ x,
                                                const float* __restrict__ W_Q0,
                                                float* __restrict__ qs_pre) {
  __shared__ __align__(16) float w0[1024];
  int tid = threadIdx.x;
#pragma unroll
  for (int i = 0; i < 4; ++i) w0[tid + i * 256] = W_Q0[tid + i * 256];
  __syncthreads();
  int b = blockIdx.x >> 3;
  int n = ((blockIdx.x & 7) << 8) + tid;
  const float4* xp = (const float4*)(x + ((size_t)(b * 2048 + n)) * 384);
  float m[32];
#pragma unroll
  for (int k = 0; k < 32; ++k) m[k] = 0.f;
  for (int t = 0; t < 12; ++t) {
#pragma unroll
    for (int i = 0; i < 8; ++i) {
      float4 v = xp[t * 8 + i];
      m[4 * i + 0] += v.x; m[4 * i + 1] += v.y; m[4 * i + 2] += v.z; m[4 * i + 3] += v.w;
    }
  }
#pragma unroll
  for (int k = 0; k < 32; ++k) m[k] *= (1.0f / 12.0f);
  float* op = qs_pre + ((size_t)(b * 2048 + n)) * 32;
#pragma unroll
  for (int q4 = 0; q4 < 8; ++q4) {
    float4 a = make_float4(0.f, 0.f, 0.f, 0.f);
    for (int k = 0; k < 32; ++k) {
      float mk = m[k];
      float4 wv = ((const float4*)(w0 + k * 32))[q4];
      a.x += mk * wv.x; a.y += mk * wv.y; a.z += mk * wv.z; a.w += mk * wv.w;
    }
    ((float4*)op)[q4] = a;
  }
}

// xmn[b,t,k] = mean_n x[b,:,t,k]
__global__ __launch_bounds__(256) void k_xmn(const float* __restrict__ x, float* __restrict__ xmn) {
  int b = blockIdx.x / 12, t = blockIdx.x % 12;
  int k = threadIdx.x & 31, sl = threadIdx.x >> 5;
  const float* xp = x + (size_t)b * 786432 + (size_t)t * 32 + k;
  float s = 0.f;
  for (int i = 0; i < 256; ++i) {
    int n = (sl << 8) + i;
    s += xp[(size_t)n * 384];
  }
  __shared__ float red[8][32];
  red[sl][k] = s;
  __syncthreads();
  if (threadIdx.x < 32) {
    float tot = 0.f;
#pragma unroll
    for (int j = 0; j < 8; ++j) tot += red[j][threadIdx.x];
    xmn[(b * 12 + t) * 32 + threadIdx.x] = tot * (1.0f / 2048.0f);
  }
}

// partial qs over n-chunks: pqs[chunk,b,dk]
__global__ __launch_bounds__(256) void k_qs_partial(const float* __restrict__ qs_pre,
                                                    const float* __restrict__ W_QS,
                                                    float* __restrict__ pqs) {
  int tid = threadIdx.x, lane = tid & 63, wid = tid >> 6;
  int n0 = blockIdx.x << 6;
  float acc[16];
#pragma unroll
  for (int b = 0; b < 16; ++b) acc[b] = 0.f;
  for (int i = 0; i < 16; ++i) {
    int n = n0 + wid * 16 + i;
    const float* wrow = W_QS + (size_t)n * 2048 + lane;
    for (int q = 0; q < 32; ++q) {
      float wv = wrow[(size_t)q * 64];
#pragma unroll
      for (int b = 0; b < 16; ++b)
        acc[b] += qs_pre[(size_t)(b * 2048 + n) * 32 + q] * wv;
    }
  }
  __shared__ float red[4][16][64];
#pragma unroll
  for (int b = 0; b < 16; ++b) red[wid][b][lane] = acc[b];
  __syncthreads();
#pragma unroll
  for (int it = 0; it < 4; ++it) {
    int idx = tid + it * 256;
    int b = idx >> 6, dk = idx & 63;
    float s = red[0][b][dk] + red[1][b][dk] + red[2][b][dk] + red[3][b][dk];
    pqs[(blockIdx.x * 16 + b) * 64 + dk] = s;
  }
}

// qt[b,dk] = ((xmn @ W_Q0).flatten) @ W_QT
__global__ __launch_bounds__(384) void k_qt(const float* __restrict__ xmn,
                                            const float* __restrict__ W_Q0,
                                            const float* __restrict__ W_QT,
                                            float* __restrict__ qt) {
  int b = blockIdx.x, tid = threadIdx.x;
  __shared__ float xp[384];
  {
    int t = tid >> 5, q = tid & 31;
    float a = 0.f;
#pragma unroll
    for (int k = 0; k < 32; ++k) a += xmn[(b * 12 + t) * 32 + k] * W_Q0[k * 32 + q];
    xp[tid] = a;
  }
  __syncthreads();
  if (tid < 64) {
    float s = 0.f;
    for (int i = 0; i < 384; ++i) s += xp[i] * W_QT[i * 64 + tid];
    qt[b * 64 + tid] = s;
  }
}

// attn[b, 0..3]=softmax(qt*scale@K_T^T), attn[b,4..7]=softmax(qs*scale@K_S^T)
__global__ __launch_bounds__(64) void k_attn(const float* __restrict__ pqs,
                                             const float* __restrict__ qt,
                                             const float* __restrict__ K_T,
                                             const float* __restrict__ K_S,
                                             float* __restrict__ attn) {
  int b = blockIdx.x, lane = threadIdx.x;
  float qsv = 0.f;
  for (int c = 0; c < 32; ++c) qsv += pqs[(c * 16 + b) * 64 + lane];
  float qtv = qt[b * 64 + lane];
  float lt[4], ls[4];
#pragma unroll
  for (int h = 0; h < 4; ++h) {
    float p = qtv * K_T[h * 64 + lane];
#pragma unroll
    for (int off = 32; off > 0; off >>= 1) p += __shfl_xor(p, off);
    lt[h] = p;
    float p2 = qsv * K_S[h * 64 + lane];
#pragma unroll
    for (int off = 32; off > 0; off >>= 1) p2 += __shfl_xor(p2, off);
    ls[h] = p2;
  }
  if (lane == 0) {
    const float scale = 0.125f;
    float mt = fmaxf(fmaxf(lt[0], lt[1]), fmaxf(lt[2], lt[3]));
    float ms = fmaxf(fmaxf(ls[0], ls[1]), fmaxf(ls[2], ls[3]));
    float et[4], es[4], st = 0.f, ss = 0.f;
#pragma unroll
    for (int h = 0; h < 4; ++h) {
      et[h] = __expf((lt[h] - mt) * scale); st += et[h];
      es[h] = __expf((ls[h] - ms) * scale); ss += es[h];
    }
#pragma unroll
    for (int h = 0; h < 4; ++h) {
      attn[b * 8 + h] = et[h] / st;
      attn[b * 8 + 4 + h] = es[h] / ss;
    }
  }
}

// ets[b,n,c] = sum_h attn_t[b,h]*V_T[h,n,c] + attn_s[b,h]*V_S[h,n,c]
__global__ __launch_bounds__(256) void k_ets(const float* __restrict__ attn,
                                             const float* __restrict__ V_T,
                                             const float* __restrict__ V_S,
                                             float* __restrict__ ets) {
  int idx = blockIdx.x * 256 + threadIdx.x;
  if (idx >= 16 * 2048 * 10) return;
  int b = idx / 20480, rem = idx % 20480;
  const float* at = attn + b * 8;
  float v = 0.f;
#pragma unroll
  for (int h = 0; h < 4; ++h)
    v += at[h] * V_T[h * 20480 + rem] + at[4 + h] * V_S[h * 20480 + rem];
  ets[idx] = v;
}

// ---------------- phase B: fused adjacency + row softmax -> bf16 ----------------

__global__ __launch_bounds__(256) void k_adj(const float* __restrict__ ets,
                                             const float* __restrict__ dis,
                                             unsigned short* __restrict__ adj) {
  __shared__ unsigned int e[2048 * 7];  // ets[b] as bf16 pairs, 7-uint stride (bank-friendly)
  int tid = threadIdx.x;
  int b = blockIdx.x >> 6;
  int n_base = (blockIdx.x & 63) << 5;
  for (int row = tid; row < 2048; row += 256) {
    const float* ep = ets + ((size_t)b * 2048 + row) * 10;
    unsigned* er = &e[row * 7];
#pragma unroll
    for (int c2 = 0; c2 < 5; ++c2)
      er[c2] = (unsigned)f2bf(ep[2 * c2]) | ((unsigned)f2bf(ep[2 * c2 + 1]) << 16);
  }
  __syncthreads();
  int lane = tid & 63, wid = tid >> 6;
  for (int j = 0; j < 8; ++j) {
    int n = n_base + wid * 8 + j;
    const float* enp = ets + ((size_t)b * 2048 + n) * 10;
    float en[10];
#pragma unroll
    for (int c = 0; c < 10; ++c) en[c] = enp[c];
    const float* drow = dis + (size_t)n * 2048;
    float s[32];
#pragma unroll
    for (int i = 0; i < 32; ++i) {
      int m = (i << 6) + lane;
      const unsigned* er = &e[m * 7];
      float dot = 0.f;
#pragma unroll
      for (int c2 = 0; c2 < 5; ++c2) {
        unsigned u = er[c2];
        dot += en[2 * c2] * __builtin_bit_cast(float, u << 16) +
               en[2 * c2 + 1] * __builtin_bit_cast(float, u & 0xffff0000u);
      }
      s[i] = fmaxf(drow[m] + dot, 0.f);
    }
    float mx = s[0];
#pragma unroll
    for (int i = 1; i < 32; ++i) mx = fmaxf(mx, s[i]);
#pragma unroll
    for (int off = 32; off > 0; off >>= 1) mx = fmaxf(mx, __shfl_xor(mx, off));
    float sum = 0.f;
#pragma unroll
    for (int i = 0; i < 32; ++i) { s[i] = __expf(s[i] - mx); sum += s[i]; }
#pragma unroll
    for (int off = 32; off > 0; off >>= 1) sum += __shfl_xor(sum, off);
    float inv = 1.0f / sum;
    unsigned short* arow = adj + ((size_t)b * 2048 + n) * 2048;
#pragma unroll
    for (int i = 0; i < 32; ++i) arow[(i << 6) + lane] = f2bf(s[i] * inv);
  }
}

// ---------------- phase C producers: z0^T and bias terms ----------------

__device__ __forceinline__ void compute_mat(const float* w, const float* xv, float* out) {
  float4 a[8];
#pragma unroll
  for (int i = 0; i < 8; ++i) a[i] = make_float4(0.f, 0.f, 0.f, 0.f);
#pragma unroll
  for (int k = 0; k < 32; ++k) {
    float xk = xv[k];
#pragma unroll
    for (int d4 = 0; d4 < 8; ++d4) {
      float4 wv = ((const float4*)(w + k * 32))[d4];
      a[d4].x += xk * wv.x; a[d4].y += xk * wv.y; a[d4].z += xk * wv.z; a[d4].w += xk * wv.w;
    }
  }
#pragma unroll
  for (int d4 = 0; d4 < 8; ++d4) {
    out[4 * d4 + 0] = a[d4].x; out[4 * d4 + 1] = a[d4].y;
    out[4 * d4 + 2] = a[d4].z; out[4 * d4 + 3] = a[d4].w;
  }
}

__device__ __forceinline__ void store32bf(unsigned short* p, const float* v) {
#pragma unroll
  for (int i = 0; i < 4; ++i) {
    uint4 u;
    u.x = (unsigned)f2bf(v[8 * i + 0]) | ((unsigned)f2bf(v[8 * i + 1]) << 16);
    u.y = (unsigned)f2bf(v[8 * i + 2]) | ((unsigned)f2bf(v[8 * i + 3]) << 16);
    u.z = (unsigned)f2bf(v[8 * i + 4]) | ((unsigned)f2bf(v[8 * i + 5]) << 16);
    u.w = (unsigned)f2bf(v[8 * i + 6]) | ((unsigned)f2bf(v[8 * i + 7]) << 16);
    ((uint4*)p)[i] = u;
  }
}

// z0T[b, t*32+d, m] = sum_k x[b,m,t,k] W2[k,d]; bias_i[b,m,t*32+d] = x @ W_s{i}
__global__ __launch_bounds__(256) void k_zb(const float* __restrict__ x,
                                            const float* __restrict__ W2,
                                            const float* __restrict__ Ws0,
                                            const float* __restrict__ Ws1,
                                            unsigned short* __restrict__ z0T,
                                            unsigned short* __restrict__ bias0,
                                            unsigned short* __restrict__ bias1) {
  __shared__ __align__(16) float w[3][1024];
  int tid = threadIdx.x;
  for (int i = tid; i < 1024; i += 256) {
    w[0][i] = W2[i]; w[1][i] = Ws0[i]; w[2][i] = Ws1[i];
  }
  __syncthreads();
  int bx = blockIdx.x;
  int b = bx / 96, r = bx % 96, t = r >> 3, mc = r & 7;
  int m = (mc << 8) + tid;
  const float4* xp = (const float4*)(x + (((size_t)(b * 2048 + m)) * 12 + t) * 32);
  float xv[32];
#pragma unroll
  for (int i = 0; i < 8; ++i) {
    float4 v = xp[i];
    xv[4 * i + 0] = v.x; xv[4 * i + 1] = v.y; xv[4 * i + 2] = v.z; xv[4 * i + 3] = v.w;
  }
  float out[32];
  compute_mat(w[0], xv, out);
  unsigned short* zp = z0T + (size_t)b * 786432 + (size_t)(t * 32) * 2048 + m;
#pragma unroll
  for (int d = 0; d < 32; ++d) zp[(size_t)d * 2048] = f2bf(out[d]);
  size_t bb = ((size_t)(b * 2048 + m)) * 384 + t * 32;
  compute_mat(w[1], xv, out);
  store32bf(bias0 + bb, out);
  compute_mat(w[2], xv, out);
  store32bf(bias1 + bb, out);
}

// ---------------- phase C: adj @ z (+bias) MFMA GEMM ----------------
// A = adj[b] [2048 x 2048] bf16 row-major (k-contig); B = zT[b] [384 x 2048] (col rows, k-contig)
// OUT_F32=0: out = z1T bf16 [384][2048]; OUT_F32=1: out = d_out f32 [2048][384]

template <int OUT_F32>
__global__ __launch_bounds__(256) void gemm_adj(const unsigned short* __restrict__ adj,
                                                const unsigned short* __restrict__ Bt,
                                                const unsigned short* __restrict__ bias,
                                                void* __restrict__ outp) {
  const int tid = threadIdx.x;
  const int lane = tid & 63;
  const int wid = tid >> 6;
  const int wr = wid >> 1, wc = wid & 1;
  const int c0 = blockIdx.x * 128;  // col tile (N)
  const int m0 = blockIdx.y * 128;  // row tile (M)
  const int b = blockIdx.z;

  __shared__ __align__(16) unsigned char smem[32768];  // As[128][64], Bs[128][64] bf16 (swizzled)

  const unsigned short* aBase = adj + ((size_t)b << 22);
  const unsigned short* bBase = Bt + (size_t)b * 786432;
  const unsigned short* gsrc[8];
  {
    const int rr = tid >> 3, j = tid & 7;
#pragma unroll
    for (int ii = 0; ii < 4; ++ii) {
      int rA = ii * 32 + rr;
      gsrc[ii] = aBase + (size_t)(m0 + rA) * 2048 + ((j ^ (rA & 7)) << 3);
      gsrc[4 + ii] = bBase + (size_t)(c0 + rA) * 2048 + ((j ^ (rA & 7)) << 3);
    }
  }
  int aoff[2][4], boff[2][4];
#pragma unroll
  for (int kk = 0; kk < 2; ++kk) {
#pragma unroll
    for (int f = 0; f < 4; ++f) {
      int c = kk * 4 + (lane >> 4);
      int rA = wr * 64 + f * 16 + (lane & 15);
      aoff[kk][f] = rA * 128 + ((c ^ (rA & 7)) << 4);
      int rB = wc * 64 + f * 16 + (lane & 15);
      boff[kk][f] = 16384 + rB * 128 + ((c ^ (rB & 7)) << 4);
    }
  }

  f32x4 acc[4][4] = {};
  const int ldsW = wid * 1024;

  for (int kt = 0; kt < 32; ++kt) {
#pragma unroll
    for (int ii = 0; ii < 4; ++ii) gload16(gsrc[ii], smem + ii * 4096 + ldsW);
#pragma unroll
    for (int ii = 0; ii < 4; ++ii) gload16(gsrc[4 + ii], smem + 16384 + ii * 4096 + ldsW);
#pragma unroll
    for (int ii = 0; ii < 8; ++ii) gsrc[ii] += 64;
    __syncthreads();
#pragma unroll
    for (int kk = 0; kk < 2; ++kk) {
      bf16x8 af[4], bfv[4];
#pragma unroll
      for (int f = 0; f < 4; ++f) af[f] = *(const bf16x8*)(smem + aoff[kk][f]);
#pragma unroll
      for (int f = 0; f < 4; ++f) bfv[f] = *(const bf16x8*)(smem + boff[kk][f]);
#pragma unroll
      for (int m = 0; m < 4; ++m)
#pragma unroll
        for (int n = 0; n < 4; ++n)
          acc[m][n] = __builtin_amdgcn_mfma_f32_16x16x32_bf16(af[m], bfv[n], acc[m][n], 0, 0, 0);
    }
    __syncthreads();
  }

  const int cl = lane & 15;
  const int r4 = (lane >> 4) << 2;
  const unsigned short* bi = bias + (size_t)b * 786432;
  if (OUT_F32) {
    float* o = (float*)outp + (size_t)b * 786432;
#pragma unroll
    for (int m = 0; m < 4; ++m) {
      int row0 = m0 + wr * 64 + m * 16 + r4;
#pragma unroll
      for (int n = 0; n < 4; ++n) {
        int col = c0 + wc * 64 + n * 16 + cl;
#pragma unroll
        for (int r = 0; r < 4; ++r) {
          int row = row0 + r;
          o[(size_t)row * 384 + col] = acc[m][n][r] + bf2f(bi[(size_t)row * 384 + col]);
        }
      }
    }
  } else {
    unsigned short* o = (unsigned short*)outp + (size_t)b * 786432;
#pragma unroll
    for (int m = 0; m < 4; ++m) {
      int row0 = m0 + wr * 64 + m * 16 + r4;
#pragma unroll
      for (int n = 0; n < 4; ++n) {
        int col = c0 + wc * 64 + n * 16 + cl;
        ushort4 pk;
        pk.x = f2bf(acc[m][n][0] + bf2f(bi[(size_t)(row0 + 0) * 384 + col]));
        pk.y = f2bf(acc[m][n][1] + bf2f(bi[(size_t)(row0 + 1) * 384 + col]));
        pk.z = f2bf(acc[m][n][2] + bf2f(bi[(size_t)(row0 + 2) * 384 + col]));
        pk.w = f2bf(acc[m][n][3] + bf2f(bi[(size_t)(row0 + 3) * 384 + col]));
        *(ushort4*)(o + (size_t)col * 2048 + row0) = pk;
      }
    }
  }
}

// ---------------- launch ----------------

extern "C" void kernel_launch(void* const* d_in, const int* in_sizes, int n_in,
                              void* d_out, int out_size, void* d_ws, size_t ws_size,
                              hipStream_t stream) {
  const float* x = (const float*)d_in[0];
  const float* dis = (const float*)d_in[1];
  const float* K_S = (const float*)d_in[2];
  const float* V_S = (const float*)d_in[3];
  const float* K_T = (const float*)d_in[4];
  const float* V_T = (const float*)d_in[5];
  const float* W_Q0 = (const float*)d_in[6];
  const float* W_QS = (const float*)d_in[7];
  const float* W_QT = (const float*)d_in[8];
  const float* W2 = (const float*)d_in[9];
  const float* W_s0 = (const float*)d_in[10];
  const float* W_s1 = (const float*)d_in[11];

  char* ws = (char*)d_ws;
  float* qs_pre = (float*)(ws + 0);                          //  4,194,304 B
  float* xmn = (float*)(ws + 4194304);                       //     24,576 B
  float* qt = (float*)(ws + 4218880);                        //      4,096 B
  float* pqs = (float*)(ws + 4222976);                       //    131,072 B
  float* attn = (float*)(ws + 4354048);                      //        512 B
  float* ets = (float*)(ws + 4354560);                       //  1,310,720 B
  unsigned short* adj = (unsigned short*)(ws + 5665280);     // 134,217,728 B
  unsigned short* z0T = (unsigned short*)(ws + 139883008);   // 25,165,824 B
  unsigned short* z1T = (unsigned short*)(ws + 165048832);   // 25,165,824 B
  unsigned short* bias0 = (unsigned short*)(ws + 190214656); // 25,165,824 B
  unsigned short* bias1 = (unsigned short*)(ws + 215380480); // 25,165,824 B -> 240,546,304 total

  k_qs_pre<<<128, 256, 0, stream>>>(x, W_Q0, qs_pre);
  k_xmn<<<192, 256, 0, stream>>>(x, xmn);
  k_qs_partial<<<32, 256, 0, stream>>>(qs_pre, W_QS, pqs);
  k_qt<<<16, 384, 0, stream>>>(xmn, W_Q0, W_QT, qt);
  k_attn<<<16, 64, 0, stream>>>(pqs, qt, K_T, K_S, attn);
  k_ets<<<1280, 256, 0, stream>>>(attn, V_T, V_S, ets);
  k_adj<<<1024, 256, 0, stream>>>(ets, dis, adj);
  k_zb<<<1536, 256, 0, stream>>>(x, W2, W_s0, W_s1, z0T, bias0, bias1);
  dim3 gg(3, 16, 16);
  gemm_adj<0><<<gg, 256, 0, stream>>>(adj, z0T, bias0, (void*)z1T);
  gemm_adj<1><<<gg, 256, 0, stream>>>(adj, z1T, bias1, d_out);
}

// Round 2
// 773.128 us; speedup vs baseline: 1.6374x; 1.6374x over previous
//
#include <hip/hip_runtime.h>

typedef __bf16 bf16x8 __attribute__((ext_vector_type(8)));
typedef float f32x4 __attribute__((ext_vector_type(4)));

__device__ __forceinline__ unsigned short f2bf(float f) {
  unsigned u = __builtin_bit_cast(unsigned, f);
  u += 0x7fffu + ((u >> 16) & 1u);
  return (unsigned short)(u >> 16);
}
__device__ __forceinline__ float bf2f(unsigned short h) {
  unsigned u = ((unsigned)h) << 16;
  return __builtin_bit_cast(float, u);
}
__device__ __forceinline__ void gload16(const void* g, void* l) {
  __builtin_amdgcn_global_load_lds((const __attribute__((address_space(1))) void*)g,
                                   (__attribute__((address_space(3))) void*)l, 16, 0, 0);
}

// ---------------- phase A: means / queries / attention / ets ----------------

// xmn[b,t,k] = mean_n x[b,:,t,k]
__global__ __launch_bounds__(256) void k_xmn(const float* __restrict__ x, float* __restrict__ xmn) {
  int b = blockIdx.x / 12, t = blockIdx.x % 12;
  int k = threadIdx.x & 31, sl = threadIdx.x >> 5;
  const float* xp = x + (size_t)b * 786432 + (size_t)t * 32 + k;
  float s = 0.f;
  for (int i = 0; i < 256; ++i) {
    int n = (sl << 8) + i;
    s += xp[(size_t)n * 384];
  }
  __shared__ float red[8][32];
  red[sl][k] = s;
  __syncthreads();
  if (threadIdx.x < 32) {
    float tot = 0.f;
#pragma unroll
    for (int j = 0; j < 8; ++j) tot += red[j][threadIdx.x];
    xmn[(b * 12 + t) * 32 + threadIdx.x] = tot * (1.0f / 2048.0f);
  }
}

// Fused: per block (4 n-values): mean_t(x) -> @W_Q0 -> contract with W_QS rows
// pqs[blk, b, dk] partial over the block's 128 W_QS rows.
__global__ __launch_bounds__(256) void k_qs(const float* __restrict__ x,
                                            const float* __restrict__ W_Q0,
                                            const float* __restrict__ W_QS,
                                            float* __restrict__ pqs) {
  __shared__ __align__(16) float w0[1024];
  __shared__ float lm[2048];  // [b][nloc*32+k]
  __shared__ float lq[2048];  // [b][nloc*32+q]
  __shared__ float red[4][16][64];
  int tid = threadIdx.x;
#pragma unroll
  for (int i = 0; i < 4; ++i) w0[tid + i * 256] = W_Q0[tid + i * 256];
  int n0 = blockIdx.x * 4;
  // step A: mean over t
#pragma unroll
  for (int j = 0; j < 8; ++j) {
    int i = tid + j * 256;
    int b = i >> 7, r = i & 127;
    int n = n0 + (r >> 5), k = r & 31;
    const float* xp = x + ((size_t)(b * 2048 + n) * 12) * 32 + k;
    float s = 0.f;
#pragma unroll
    for (int t = 0; t < 12; ++t) s += xp[t * 32];
    lm[i] = s * (1.0f / 12.0f);
  }
  __syncthreads();
  // step B: @ W_Q0
#pragma unroll
  for (int j = 0; j < 8; ++j) {
    int i = tid + j * 256;
    int br = i >> 5, q = i & 31;
    const float* mrow = &lm[br * 32];
    float a = 0.f;
#pragma unroll
    for (int k = 0; k < 32; ++k) a += mrow[k] * w0[k * 32 + q];
    lq[i] = a;
  }
  __syncthreads();
  // step C: contract with W_QS rows [n0*32, n0*32+128)
  int lane = tid & 63, wid = tid >> 6;
  float acc[16];
#pragma unroll
  for (int b = 0; b < 16; ++b) acc[b] = 0.f;
  for (int rl = 0; rl < 32; ++rl) {
    int r = wid * 32 + rl;
    float wv = W_QS[(size_t)(n0 * 32 + r) * 64 + lane];
#pragma unroll
    for (int b = 0; b < 16; ++b) acc[b] += lq[b * 128 + r] * wv;
  }
#pragma unroll
  for (int b = 0; b < 16; ++b) red[wid][b][lane] = acc[b];
  __syncthreads();
#pragma unroll
  for (int it = 0; it < 4; ++it) {
    int idx = tid + it * 256;
    float s = red[0][idx >> 6][idx & 63] + red[1][idx >> 6][idx & 63] +
              red[2][idx >> 6][idx & 63] + red[3][idx >> 6][idx & 63];
    pqs[(size_t)blockIdx.x * 1024 + idx] = s;
  }
}

__global__ __launch_bounds__(256) void k_qs_reduce(const float* __restrict__ pqs,
                                                   float* __restrict__ qs) {
  int b = blockIdx.x, lane = threadIdx.x & 63, wid = threadIdx.x >> 6;
  float s = 0.f;
  for (int c = wid; c < 512; c += 4) s += pqs[(size_t)c * 1024 + b * 64 + lane];
  __shared__ float red[4][64];
  red[wid][lane] = s;
  __syncthreads();
  if (threadIdx.x < 64)
    qs[b * 64 + threadIdx.x] =
        red[0][threadIdx.x] + red[1][threadIdx.x] + red[2][threadIdx.x] + red[3][threadIdx.x];
}

// qt[b,dk] = ((xmn @ W_Q0).flatten) @ W_QT
__global__ __launch_bounds__(384) void k_qt(const float* __restrict__ xmn,
                                            const float* __restrict__ W_Q0,
                                            const float* __restrict__ W_QT,
                                            float* __restrict__ qt) {
  int b = blockIdx.x, tid = threadIdx.x;
  __shared__ float xp[384];
  {
    int t = tid >> 5, q = tid & 31;
    float a = 0.f;
#pragma unroll
    for (int k = 0; k < 32; ++k) a += xmn[(b * 12 + t) * 32 + k] * W_Q0[k * 32 + q];
    xp[tid] = a;
  }
  __syncthreads();
  if (tid < 64) {
    float s = 0.f;
    for (int i = 0; i < 384; ++i) s += xp[i] * W_QT[i * 64 + tid];
    qt[b * 64 + tid] = s;
  }
}

// attn[b, 0..3]=softmax(qt*scale@K_T^T), attn[b,4..7]=softmax(qs*scale@K_S^T)
__global__ __launch_bounds__(64) void k_attn(const float* __restrict__ qs,
                                             const float* __restrict__ qt,
                                             const float* __restrict__ K_T,
                                             const float* __restrict__ K_S,
                                             float* __restrict__ attn) {
  int b = blockIdx.x, lane = threadIdx.x;
  float qsv = qs[b * 64 + lane];
  float qtv = qt[b * 64 + lane];
  float lt[4], ls[4];
#pragma unroll
  for (int h = 0; h < 4; ++h) {
    float p = qtv * K_T[h * 64 + lane];
#pragma unroll
    for (int off = 32; off > 0; off >>= 1) p += __shfl_xor(p, off);
    lt[h] = p;
    float p2 = qsv * K_S[h * 64 + lane];
#pragma unroll
    for (int off = 32; off > 0; off >>= 1) p2 += __shfl_xor(p2, off);
    ls[h] = p2;
  }
  if (lane == 0) {
    const float scale = 0.125f;
    float mt = fmaxf(fmaxf(lt[0], lt[1]), fmaxf(lt[2], lt[3]));
    float ms = fmaxf(fmaxf(ls[0], ls[1]), fmaxf(ls[2], ls[3]));
    float et[4], es[4], st = 0.f, ss = 0.f;
#pragma unroll
    for (int h = 0; h < 4; ++h) {
      et[h] = __expf((lt[h] - mt) * scale); st += et[h];
      es[h] = __expf((ls[h] - ms) * scale); ss += es[h];
    }
#pragma unroll
    for (int h = 0; h < 4; ++h) {
      attn[b * 8 + h] = et[h] / st;
      attn[b * 8 + 4 + h] = es[h] / ss;
    }
  }
}

// ets[b,n,c] = sum_h attn_t[b,h]*V_T[h,n,c] + attn_s[b,h]*V_S[h,n,c]
__global__ __launch_bounds__(256) void k_ets(const float* __restrict__ attn,
                                             const float* __restrict__ V_T,
                                             const float* __restrict__ V_S,
                                             float* __restrict__ ets) {
  int idx = blockIdx.x * 256 + threadIdx.x;
  if (idx >= 16 * 2048 * 10) return;
  int b = idx / 20480, rem = idx % 20480;
  const float* at = attn + b * 8;
  float v = 0.f;
#pragma unroll
  for (int h = 0; h < 4; ++h)
    v += at[h] * V_T[h * 20480 + rem] + at[4 + h] * V_S[h * 20480 + rem];
  ets[idx] = v;
}

// ---------------- phase B: fused adjacency + row softmax -> bf16 ----------------

__global__ __launch_bounds__(256) void k_adj(const float* __restrict__ ets,
                                             const float* __restrict__ dis,
                                             unsigned short* __restrict__ adj) {
  __shared__ unsigned int e[2048 * 7];
  int tid = threadIdx.x;
  int b = blockIdx.x >> 6;
  int n_base = (blockIdx.x & 63) << 5;
  for (int row = tid; row < 2048; row += 256) {
    const float* ep = ets + ((size_t)b * 2048 + row) * 10;
    unsigned* er = &e[row * 7];
#pragma unroll
    for (int c2 = 0; c2 < 5; ++c2)
      er[c2] = (unsigned)f2bf(ep[2 * c2]) | ((unsigned)f2bf(ep[2 * c2 + 1]) << 16);
  }
  __syncthreads();
  int lane = tid & 63, wid = tid >> 6;
  for (int j = 0; j < 8; ++j) {
    int n = n_base + wid * 8 + j;
    const float* enp = ets + ((size_t)b * 2048 + n) * 10;
    float en[10];
#pragma unroll
    for (int c = 0; c < 10; ++c) en[c] = enp[c];
    const float* drow = dis + (size_t)n * 2048;
    float s[32];
#pragma unroll
    for (int i = 0; i < 32; ++i) {
      int m = (i << 6) + lane;
      const unsigned* er = &e[m * 7];
      float dot = 0.f;
#pragma unroll
      for (int c2 = 0; c2 < 5; ++c2) {
        unsigned u = er[c2];
        dot += en[2 * c2] * __builtin_bit_cast(float, u << 16) +
               en[2 * c2 + 1] * __builtin_bit_cast(float, u & 0xffff0000u);
      }
      s[i] = fmaxf(drow[m] + dot, 0.f);
    }
    float mx = s[0];
#pragma unroll
    for (int i = 1; i < 32; ++i) mx = fmaxf(mx, s[i]);
#pragma unroll
    for (int off = 32; off > 0; off >>= 1) mx = fmaxf(mx, __shfl_xor(mx, off));
    float sum = 0.f;
#pragma unroll
    for (int i = 0; i < 32; ++i) { s[i] = __expf(s[i] - mx); sum += s[i]; }
#pragma unroll
    for (int off = 32; off > 0; off >>= 1) sum += __shfl_xor(sum, off);
    float inv = 1.0f / sum;
    unsigned short* arow = adj + ((size_t)b * 2048 + n) * 2048;
#pragma unroll
    for (int i = 0; i < 32; ++i) arow[(i << 6) + lane] = f2bf(s[i] * inv);
  }
}

// ---------------- phase C producers: z0^T and bias terms ----------------

__device__ __forceinline__ void compute_mat(const float* w, const float* xv, float* out) {
  float4 a[8];
#pragma unroll
  for (int i = 0; i < 8; ++i) a[i] = make_float4(0.f, 0.f, 0.f, 0.f);
#pragma unroll
  for (int k = 0; k < 32; ++k) {
    float xk = xv[k];
#pragma unroll
    for (int d4 = 0; d4 < 8; ++d4) {
      float4 wv = ((const float4*)(w + k * 32))[d4];
      a[d4].x += xk * wv.x; a[d4].y += xk * wv.y; a[d4].z += xk * wv.z; a[d4].w += xk * wv.w;
    }
  }
#pragma unroll
  for (int d4 = 0; d4 < 8; ++d4) {
    out[4 * d4 + 0] = a[d4].x; out[4 * d4 + 1] = a[d4].y;
    out[4 * d4 + 2] = a[d4].z; out[4 * d4 + 3] = a[d4].w;
  }
}

__device__ __forceinline__ void store32bf(unsigned short* p, const float* v) {
#pragma unroll
  for (int i = 0; i < 4; ++i) {
    uint4 u;
    u.x = (unsigned)f2bf(v[8 * i + 0]) | ((unsigned)f2bf(v[8 * i + 1]) << 16);
    u.y = (unsigned)f2bf(v[8 * i + 2]) | ((unsigned)f2bf(v[8 * i + 3]) << 16);
    u.z = (unsigned)f2bf(v[8 * i + 4]) | ((unsigned)f2bf(v[8 * i + 5]) << 16);
    u.w = (unsigned)f2bf(v[8 * i + 6]) | ((unsigned)f2bf(v[8 * i + 7]) << 16);
    ((uint4*)p)[i] = u;
  }
}

__global__ __launch_bounds__(256) void k_zb(const float* __restrict__ x,
                                            const float* __restrict__ W2,
                                            const float* __restrict__ Ws0,
                                            const float* __restrict__ Ws1,
                                            unsigned short* __restrict__ z0T,
                                            unsigned short* __restrict__ bias0,
                                            unsigned short* __restrict__ bias1) {
  __shared__ __align__(16) float w[3][1024];
  int tid = threadIdx.x;
  for (int i = tid; i < 1024; i += 256) {
    w[0][i] = W2[i]; w[1][i] = Ws0[i]; w[2][i] = Ws1[i];
  }
  __syncthreads();
  int bx = blockIdx.x;
  int b = bx / 96, r = bx % 96, t = r >> 3, mc = r & 7;
  int m = (mc << 8) + tid;
  const float4* xp = (const float4*)(x + (((size_t)(b * 2048 + m)) * 12 + t) * 32);
  float xv[32];
#pragma unroll
  for (int i = 0; i < 8; ++i) {
    float4 v = xp[i];
    xv[4 * i + 0] = v.x; xv[4 * i + 1] = v.y; xv[4 * i + 2] = v.z; xv[4 * i + 3] = v.w;
  }
  float out[32];
  compute_mat(w[0], xv, out);
  unsigned short* zp = z0T + (size_t)b * 786432 + (size_t)(t * 32) * 2048 + m;
#pragma unroll
  for (int d = 0; d < 32; ++d) zp[(size_t)d * 2048] = f2bf(out[d]);
  size_t bb = ((size_t)(b * 2048 + m)) * 384 + t * 32;
  compute_mat(w[1], xv, out);
  store32bf(bias0 + bb, out);
  compute_mat(w[2], xv, out);
  store32bf(bias1 + bb, out);
}

// ---------------- phase C: adj @ z (+bias) MFMA GEMM ----------------

template <int OUT_F32>
__global__ __launch_bounds__(256) void gemm_adj(const unsigned short* __restrict__ adj,
                                                const unsigned short* __restrict__ Bt,
                                                const unsigned short* __restrict__ bias,
                                                void* __restrict__ outp) {
  const int tid = threadIdx.x;
  const int lane = tid & 63;
  const int wid = tid >> 6;
  const int wr = wid >> 1, wc = wid & 1;
  const int c0 = blockIdx.x * 128;
  const int m0 = blockIdx.y * 128;
  const int b = blockIdx.z;

  __shared__ __align__(16) unsigned char smem[32768];

  const unsigned short* aBase = adj + ((size_t)b << 22);
  const unsigned short* bBase = Bt + (size_t)b * 786432;
  const unsigned short* gsrc[8];
  {
    const int rr = tid >> 3, j = tid & 7;
#pragma unroll
    for (int ii = 0; ii < 4; ++ii) {
      int rA = ii * 32 + rr;
      gsrc[ii] = aBase + (size_t)(m0 + rA) * 2048 + ((j ^ (rA & 7)) << 3);
      gsrc[4 + ii] = bBase + (size_t)(c0 + rA) * 2048 + ((j ^ (rA & 7)) << 3);
    }
  }
  int aoff[2][4], boff[2][4];
#pragma unroll
  for (int kk = 0; kk < 2; ++kk) {
#pragma unroll
    for (int f = 0; f < 4; ++f) {
      int c = kk * 4 + (lane >> 4);
      int rA = wr * 64 + f * 16 + (lane & 15);
      aoff[kk][f] = rA * 128 + ((c ^ (rA & 7)) << 4);
      int rB = wc * 64 + f * 16 + (lane & 15);
      boff[kk][f] = 16384 + rB * 128 + ((c ^ (rB & 7)) << 4);
    }
  }

  f32x4 acc[4][4] = {};
  const int ldsW = wid * 1024;

  for (int kt = 0; kt < 32; ++kt) {
#pragma unroll
    for (int ii = 0; ii < 4; ++ii) gload16(gsrc[ii], smem + ii * 4096 + ldsW);
#pragma unroll
    for (int ii = 0; ii < 4; ++ii) gload16(gsrc[4 + ii], smem + 16384 + ii * 4096 + ldsW);
#pragma unroll
    for (int ii = 0; ii < 8; ++ii) gsrc[ii] += 64;
    __syncthreads();
#pragma unroll
    for (int kk = 0; kk < 2; ++kk) {
      bf16x8 af[4], bfv[4];
#pragma unroll
      for (int f = 0; f < 4; ++f) af[f] = *(const bf16x8*)(smem + aoff[kk][f]);
#pragma unroll
      for (int f = 0; f < 4; ++f) bfv[f] = *(const bf16x8*)(smem + boff[kk][f]);
#pragma unroll
      for (int m = 0; m < 4; ++m)
#pragma unroll
        for (int n = 0; n < 4; ++n)
          acc[m][n] = __builtin_amdgcn_mfma_f32_16x16x32_bf16(af[m], bfv[n], acc[m][n], 0, 0, 0);
    }
    __syncthreads();
  }

  const int cl = lane & 15;
  const int r4 = (lane >> 4) << 2;
  const unsigned short* bi = bias + (size_t)b * 786432;
  if (OUT_F32) {
    float* o = (float*)outp + (size_t)b * 786432;
#pragma unroll
    for (int m = 0; m < 4; ++m) {
      int row0 = m0 + wr * 64 + m * 16 + r4;
#pragma unroll
      for (int n = 0; n < 4; ++n) {
        int col = c0 + wc * 64 + n * 16 + cl;
#pragma unroll
        for (int r = 0; r < 4; ++r) {
          int row = row0 + r;
          o[(size_t)row * 384 + col] = acc[m][n][r] + bf2f(bi[(size_t)row * 384 + col]);
        }
      }
    }
  } else {
    unsigned short* o = (unsigned short*)outp + (size_t)b * 786432;
#pragma unroll
    for (int m = 0; m < 4; ++m) {
      int row0 = m0 + wr * 64 + m * 16 + r4;
#pragma unroll
      for (int n = 0; n < 4; ++n) {
        int col = c0 + wc * 64 + n * 16 + cl;
        ushort4 pk;
        pk.x = f2bf(acc[m][n][0] + bf2f(bi[(size_t)(row0 + 0) * 384 + col]));
        pk.y = f2bf(acc[m][n][1] + bf2f(bi[(size_t)(row0 + 1) * 384 + col]));
        pk.z = f2bf(acc[m][n][2] + bf2f(bi[(size_t)(row0 + 2) * 384 + col]));
        pk.w = f2bf(acc[m][n][3] + bf2f(bi[(size_t)(row0 + 3) * 384 + col]));
        *(ushort4*)(o + (size_t)col * 2048 + row0) = pk;
      }
    }
  }
}

// ---------------- launch ----------------

extern "C" void kernel_launch(void* const* d_in, const int* in_sizes, int n_in,
                              void* d_out, int out_size, void* d_ws, size_t ws_size,
                              hipStream_t stream) {
  const float* x = (const float*)d_in[0];
  const float* dis = (const float*)d_in[1];
  const float* K_S = (const float*)d_in[2];
  const float* V_S = (const float*)d_in[3];
  const float* K_T = (const float*)d_in[4];
  const float* V_T = (const float*)d_in[5];
  const float* W_Q0 = (const float*)d_in[6];
  const float* W_QS = (const float*)d_in[7];
  const float* W_QT = (const float*)d_in[8];
  const float* W2 = (const float*)d_in[9];
  const float* W_s0 = (const float*)d_in[10];
  const float* W_s1 = (const float*)d_in[11];

  char* ws = (char*)d_ws;
  float* xmn = (float*)(ws + 0);                             //     24,576 B
  float* qt = (float*)(ws + 24576);                          //      4,096 B
  float* pqs = (float*)(ws + 28672);                         //  2,097,152 B
  float* qs = (float*)(ws + 2125824);                        //      4,096 B
  float* attn = (float*)(ws + 2129920);                      //        512 B
  float* ets = (float*)(ws + 2130432);                       //  1,310,720 B
  unsigned short* adj = (unsigned short*)(ws + 3441152);     // 134,217,728 B
  unsigned short* z0T = (unsigned short*)(ws + 137658880);   // 25,165,824 B
  unsigned short* z1T = (unsigned short*)(ws + 162824704);   // 25,165,824 B
  unsigned short* bias0 = (unsigned short*)(ws + 187990528); // 25,165,824 B
  unsigned short* bias1 = (unsigned short*)(ws + 213156352); // 25,165,824 B

  k_xmn<<<192, 256, 0, stream>>>(x, xmn);
  k_qs<<<512, 256, 0, stream>>>(x, W_Q0, W_QS, pqs);
  k_qs_reduce<<<16, 256, 0, stream>>>(pqs, qs);
  k_qt<<<16, 384, 0, stream>>>(xmn, W_Q0, W_QT, qt);
  k_attn<<<16, 64, 0, stream>>>(qs, qt, K_T, K_S, attn);
  k_ets<<<1280, 256, 0, stream>>>(attn, V_T, V_S, ets);
  k_adj<<<1024, 256, 0, stream>>>(ets, dis, adj);
  k_zb<<<1536, 256, 0, stream>>>(x, W2, W_s0, W_s1, z0T, bias0, bias1);
  dim3 gg(3, 16, 16);
  gemm_adj<0><<<gg, 256, 0, stream>>>(adj, z0T, bias0, (void*)z1T);
  gemm_adj<1><<<gg, 256, 0, stream>>>(adj, z1T, bias1, d_out);
}

// Round 3
// 472.596 us; speedup vs baseline: 2.6786x; 1.6359x over previous
//
#include <hip/hip_runtime.h>

typedef __bf16 bf16x8 __attribute__((ext_vector_type(8)));
typedef float f32x4 __attribute__((ext_vector_type(4)));

__device__ __forceinline__ unsigned short f2bf(float f) {
  unsigned u = __builtin_bit_cast(unsigned, f);
  u += 0x7fffu + ((u >> 16) & 1u);
  return (unsigned short)(u >> 16);
}
__device__ __forceinline__ float bf2f(unsigned short h) {
  unsigned u = ((unsigned)h) << 16;
  return __builtin_bit_cast(float, u);
}
__device__ __forceinline__ void gload16(const void* g, void* l) {
  __builtin_amdgcn_global_load_lds((const __attribute__((address_space(1))) void*)g,
                                   (__attribute__((address_space(3))) void*)l, 16, 0, 0);
}

// ---------------- phase A: means / queries / attention / ets ----------------

// xmn[b,t,k] = mean_n x[b,:,t,k]
__global__ __launch_bounds__(256) void k_xmn(const float* __restrict__ x, float* __restrict__ xmn) {
  int b = blockIdx.x / 12, t = blockIdx.x % 12;
  int k = threadIdx.x & 31, sl = threadIdx.x >> 5;
  const float* xp = x + (size_t)b * 786432 + (size_t)t * 32 + k;
  float s = 0.f;
  for (int i = 0; i < 256; ++i) {
    int n = (sl << 8) + i;
    s += xp[(size_t)n * 384];
  }
  __shared__ float red[8][32];
  red[sl][k] = s;
  __syncthreads();
  if (threadIdx.x < 32) {
    float tot = 0.f;
#pragma unroll
    for (int j = 0; j < 8; ++j) tot += red[j][threadIdx.x];
    xmn[(b * 12 + t) * 32 + threadIdx.x] = tot * (1.0f / 2048.0f);
  }
}

// Fused: per block (4 n-values): mean_t(x) -> @W_Q0 -> contract with W_QS rows
__global__ __launch_bounds__(256) void k_qs(const float* __restrict__ x,
                                            const float* __restrict__ W_Q0,
                                            const float* __restrict__ W_QS,
                                            float* __restrict__ pqs) {
  __shared__ __align__(16) float w0[1024];
  __shared__ float lm[2048];
  __shared__ float lq[2048];
  __shared__ float red[4][16][64];
  int tid = threadIdx.x;
#pragma unroll
  for (int i = 0; i < 4; ++i) w0[tid + i * 256] = W_Q0[tid + i * 256];
  int n0 = blockIdx.x * 4;
#pragma unroll
  for (int j = 0; j < 8; ++j) {
    int i = tid + j * 256;
    int b = i >> 7, r = i & 127;
    int n = n0 + (r >> 5), k = r & 31;
    const float* xp = x + ((size_t)(b * 2048 + n) * 12) * 32 + k;
    float s = 0.f;
#pragma unroll
    for (int t = 0; t < 12; ++t) s += xp[t * 32];
    lm[i] = s * (1.0f / 12.0f);
  }
  __syncthreads();
#pragma unroll
  for (int j = 0; j < 8; ++j) {
    int i = tid + j * 256;
    int br = i >> 5, q = i & 31;
    const float* mrow = &lm[br * 32];
    float a = 0.f;
#pragma unroll
    for (int k = 0; k < 32; ++k) a += mrow[k] * w0[k * 32 + q];
    lq[i] = a;
  }
  __syncthreads();
  int lane = tid & 63, wid = tid >> 6;
  float acc[16];
#pragma unroll
  for (int b = 0; b < 16; ++b) acc[b] = 0.f;
  for (int rl = 0; rl < 32; ++rl) {
    int r = wid * 32 + rl;
    float wv = W_QS[(size_t)(n0 * 32 + r) * 64 + lane];
#pragma unroll
    for (int b = 0; b < 16; ++b) acc[b] += lq[b * 128 + r] * wv;
  }
#pragma unroll
  for (int b = 0; b < 16; ++b) red[wid][b][lane] = acc[b];
  __syncthreads();
#pragma unroll
  for (int it = 0; it < 4; ++it) {
    int idx = tid + it * 256;
    float s = red[0][idx >> 6][idx & 63] + red[1][idx >> 6][idx & 63] +
              red[2][idx >> 6][idx & 63] + red[3][idx >> 6][idx & 63];
    pqs[(size_t)blockIdx.x * 1024 + idx] = s;
  }
}

__global__ __launch_bounds__(256) void k_qs_reduce(const float* __restrict__ pqs,
                                                   float* __restrict__ qs) {
  int b = blockIdx.x, lane = threadIdx.x & 63, wid = threadIdx.x >> 6;
  float s = 0.f;
  for (int c = wid; c < 512; c += 4) s += pqs[(size_t)c * 1024 + b * 64 + lane];
  __shared__ float red[4][64];
  red[wid][lane] = s;
  __syncthreads();
  if (threadIdx.x < 64)
    qs[b * 64 + threadIdx.x] =
        red[0][threadIdx.x] + red[1][threadIdx.x] + red[2][threadIdx.x] + red[3][threadIdx.x];
}

// qt[b,dk] = ((xmn @ W_Q0).flatten) @ W_QT
__global__ __launch_bounds__(384) void k_qt(const float* __restrict__ xmn,
                                            const float* __restrict__ W_Q0,
                                            const float* __restrict__ W_QT,
                                            float* __restrict__ qt) {
  int b = blockIdx.x, tid = threadIdx.x;
  __shared__ float xp[384];
  {
    int t = tid >> 5, q = tid & 31;
    float a = 0.f;
#pragma unroll
    for (int k = 0; k < 32; ++k) a += xmn[(b * 12 + t) * 32 + k] * W_Q0[k * 32 + q];
    xp[tid] = a;
  }
  __syncthreads();
  if (tid < 64) {
    float s = 0.f;
    for (int i = 0; i < 384; ++i) s += xp[i] * W_QT[i * 64 + tid];
    qt[b * 64 + tid] = s;
  }
}

__global__ __launch_bounds__(64) void k_attn(const float* __restrict__ qs,
                                             const float* __restrict__ qt,
                                             const float* __restrict__ K_T,
                                             const float* __restrict__ K_S,
                                             float* __restrict__ attn) {
  int b = blockIdx.x, lane = threadIdx.x;
  float qsv = qs[b * 64 + lane];
  float qtv = qt[b * 64 + lane];
  float lt[4], ls[4];
#pragma unroll
  for (int h = 0; h < 4; ++h) {
    float p = qtv * K_T[h * 64 + lane];
#pragma unroll
    for (int off = 32; off > 0; off >>= 1) p += __shfl_xor(p, off);
    lt[h] = p;
    float p2 = qsv * K_S[h * 64 + lane];
#pragma unroll
    for (int off = 32; off > 0; off >>= 1) p2 += __shfl_xor(p2, off);
    ls[h] = p2;
  }
  if (lane == 0) {
    const float scale = 0.125f;
    float mt = fmaxf(fmaxf(lt[0], lt[1]), fmaxf(lt[2], lt[3]));
    float ms = fmaxf(fmaxf(ls[0], ls[1]), fmaxf(ls[2], ls[3]));
    float et[4], es[4], st = 0.f, ss = 0.f;
#pragma unroll
    for (int h = 0; h < 4; ++h) {
      et[h] = __expf((lt[h] - mt) * scale); st += et[h];
      es[h] = __expf((ls[h] - ms) * scale); ss += es[h];
    }
#pragma unroll
    for (int h = 0; h < 4; ++h) {
      attn[b * 8 + h] = et[h] / st;
      attn[b * 8 + 4 + h] = es[h] / ss;
    }
  }
}

// ets_bf[b][n][16] = bf16 of sum_h attn_t[b,h]*V_T[h,n,:] + attn_s[b,h]*V_S[h,n,:], k>=10 zero
__global__ __launch_bounds__(256) void k_ets(const float* __restrict__ attn,
                                             const float* __restrict__ V_T,
                                             const float* __restrict__ V_S,
                                             unsigned short* __restrict__ ets_bf) {
  int idx = blockIdx.x * 256 + threadIdx.x;  // (b,n)
  int b = idx >> 11, n = idx & 2047;
  const float* at = attn + b * 8;
  float a0 = at[0], a1 = at[1], a2 = at[2], a3 = at[3];
  float s0 = at[4], s1 = at[5], s2 = at[6], s3 = at[7];
  float v[10];
#pragma unroll
  for (int c = 0; c < 10; ++c) {
    int o = n * 10 + c;
    v[c] = a0 * V_T[o] + a1 * V_T[20480 + o] + a2 * V_T[40960 + o] + a3 * V_T[61440 + o] +
           s0 * V_S[o] + s1 * V_S[20480 + o] + s2 * V_S[40960 + o] + s3 * V_S[61440 + o];
  }
  uint4 lo, hi;
  lo.x = (unsigned)f2bf(v[0]) | ((unsigned)f2bf(v[1]) << 16);
  lo.y = (unsigned)f2bf(v[2]) | ((unsigned)f2bf(v[3]) << 16);
  lo.z = (unsigned)f2bf(v[4]) | ((unsigned)f2bf(v[5]) << 16);
  lo.w = (unsigned)f2bf(v[6]) | ((unsigned)f2bf(v[7]) << 16);
  hi.x = (unsigned)f2bf(v[8]) | ((unsigned)f2bf(v[9]) << 16);
  hi.y = 0; hi.z = 0; hi.w = 0;
  *(uint4*)(ets_bf + (size_t)idx * 16) = lo;
  *(uint4*)(ets_bf + (size_t)idx * 16 + 8) = hi;
}

// ---------------- phase B: MFMA adjacency + row softmax -> bf16 ----------------
// block: 512 thr (8 waves), strip of 16 rows x 2048 cols; wave w owns cols [w*256, w*256+256)

__global__ __launch_bounds__(512, 4) void k_adj(const unsigned short* __restrict__ ets_bf,
                                                const float* __restrict__ dis,
                                                unsigned short* __restrict__ adj) {
  __shared__ __align__(16) unsigned char Bsh[65536];  // ets_bf[b] staged; reused as transpose buf
  __shared__ float st_max[8][16];
  __shared__ float st_sum[8][16];
  __shared__ float rowmax_s[16];
  __shared__ float rowinv_s[16];

  const int tid = threadIdx.x;
  const int lane = tid & 63;
  const int w = tid >> 6;  // wave 0..7
  const int cl = lane & 15;
  const int g = lane >> 4;  // 0..3
  const int b = blockIdx.x >> 7;
  const int n0 = (blockIdx.x & 127) << 4;

  // stage all 2048 nodes (64KB) linearly
  const unsigned char* gsrc = (const unsigned char*)(ets_bf + (size_t)b * 32768);
#pragma unroll
  for (int it = 0; it < 8; ++it)
    gload16(gsrc + it * 8192 + tid * 16, Bsh + it * 8192 + (w << 10));
  __syncthreads();

  // A fragment: rows n0..n0+15, lane: row=cl, k=(g&1)*8+e (g>=2 lanes zeroed)
  uint4 araw = *(const uint4*)(ets_bf + ((size_t)b * 2048 + n0 + cl) * 16 + (g & 1) * 8);
  if (g >= 2) { araw.x = 0; araw.y = 0; araw.z = 0; araw.w = 0; }
  bf16x8 afrag = __builtin_bit_cast(bf16x8, araw);

  // MFMA: 16 col tiles
  f32x4 acc[16];
  const int cbase = (w << 8) + cl;
#pragma unroll
  for (int n = 0; n < 16; ++n) {
    uint4 braw = *(const uint4*)(Bsh + (size_t)(cbase + n * 16) * 32 + (g & 1) * 16);
    if (g >= 2) { braw.x = 0; braw.y = 0; braw.z = 0; braw.w = 0; }
    bf16x8 bfrag = __builtin_bit_cast(bf16x8, braw);
    acc[n] = __builtin_amdgcn_mfma_f32_16x16x32_bf16(afrag, bfrag, (f32x4){0.f, 0.f, 0.f, 0.f},
                                                     0, 0, 0);
  }

  // + dis, relu, track row max  (row = g*4+j, col = w*256 + n*16 + cl)
  float mx[4] = {-1e30f, -1e30f, -1e30f, -1e30f};
  const float* dbase = dis + (size_t)(n0 + g * 4) * 2048 + (w << 8) + cl;
#pragma unroll
  for (int n = 0; n < 16; ++n) {
#pragma unroll
    for (int j = 0; j < 4; ++j) {
      float s = fmaxf(acc[n][j] + dbase[(size_t)j * 2048 + n * 16], 0.f);
      acc[n][j] = s;
      mx[j] = fmaxf(mx[j], s);
    }
  }
#pragma unroll
  for (int j = 0; j < 4; ++j) {
    mx[j] = fmaxf(mx[j], __shfl_xor(mx[j], 1));
    mx[j] = fmaxf(mx[j], __shfl_xor(mx[j], 2));
    mx[j] = fmaxf(mx[j], __shfl_xor(mx[j], 4));
    mx[j] = fmaxf(mx[j], __shfl_xor(mx[j], 8));
  }
  if (cl == 0) {
#pragma unroll
    for (int j = 0; j < 4; ++j) st_max[w][g * 4 + j] = mx[j];
  }
  __syncthreads();
  if (tid < 16) {
    float m = st_max[0][tid];
#pragma unroll
    for (int ww = 1; ww < 8; ++ww) m = fmaxf(m, st_max[ww][tid]);
    rowmax_s[tid] = m;
  }
  __syncthreads();

  float rm[4], sm[4] = {0.f, 0.f, 0.f, 0.f};
#pragma unroll
  for (int j = 0; j < 4; ++j) rm[j] = rowmax_s[g * 4 + j];
#pragma unroll
  for (int n = 0; n < 16; ++n) {
#pragma unroll
    for (int j = 0; j < 4; ++j) {
      float e = __expf(acc[n][j] - rm[j]);
      acc[n][j] = e;
      sm[j] += e;
    }
  }
#pragma unroll
  for (int j = 0; j < 4; ++j) {
    sm[j] += __shfl_xor(sm[j], 1);
    sm[j] += __shfl_xor(sm[j], 2);
    sm[j] += __shfl_xor(sm[j], 4);
    sm[j] += __shfl_xor(sm[j], 8);
  }
  if (cl == 0) {
#pragma unroll
    for (int j = 0; j < 4; ++j) st_sum[w][g * 4 + j] = sm[j];
  }
  __syncthreads();
  if (tid < 16) {
    float s = st_sum[0][tid];
#pragma unroll
    for (int ww = 1; ww < 8; ++ww) s += st_sum[ww][tid];
    rowinv_s[tid] = 1.0f / s;
  }
  __syncthreads();  // also: all waves done reading Bsh -> safe to reuse

  // normalize + pack into per-wave transpose buffer [16 rows][256 cols]
  unsigned short* Tw = (unsigned short*)Bsh + (w << 12);
  float inv[4];
#pragma unroll
  for (int j = 0; j < 4; ++j) inv[j] = rowinv_s[g * 4 + j];
#pragma unroll
  for (int n = 0; n < 16; ++n) {
#pragma unroll
    for (int j = 0; j < 4; ++j)
      Tw[(g * 4 + j) * 256 + n * 16 + cl] = f2bf(acc[n][j] * inv[j]);
  }
  __syncthreads();

  // coalesced store: one full 512B row-chunk per wave-instr
  unsigned short* obase = adj + ((size_t)b * 2048 + n0) * 2048 + (w << 8);
#pragma unroll
  for (int r = 0; r < 16; ++r) {
    uint2 v = *(const uint2*)(Tw + r * 256 + lane * 4);
    *(uint2*)(obase + (size_t)r * 2048 + lane * 4) = v;
  }
}

// ---------------- phase C producers: z0^T and bias terms ----------------

__device__ __forceinline__ void compute_mat(const float* w, const float* xv, float* out) {
  float4 a[8];
#pragma unroll
  for (int i = 0; i < 8; ++i) a[i] = make_float4(0.f, 0.f, 0.f, 0.f);
#pragma unroll
  for (int k = 0; k < 32; ++k) {
    float xk = xv[k];
#pragma unroll
    for (int d4 = 0; d4 < 8; ++d4) {
      float4 wv = ((const float4*)(w + k * 32))[d4];
      a[d4].x += xk * wv.x; a[d4].y += xk * wv.y; a[d4].z += xk * wv.z; a[d4].w += xk * wv.w;
    }
  }
#pragma unroll
  for (int d4 = 0; d4 < 8; ++d4) {
    out[4 * d4 + 0] = a[d4].x; out[4 * d4 + 1] = a[d4].y;
    out[4 * d4 + 2] = a[d4].z; out[4 * d4 + 3] = a[d4].w;
  }
}

__device__ __forceinline__ void store32bf(unsigned short* p, const float* v) {
#pragma unroll
  for (int i = 0; i < 4; ++i) {
    uint4 u;
    u.x = (unsigned)f2bf(v[8 * i + 0]) | ((unsigned)f2bf(v[8 * i + 1]) << 16);
    u.y = (unsigned)f2bf(v[8 * i + 2]) | ((unsigned)f2bf(v[8 * i + 3]) << 16);
    u.z = (unsigned)f2bf(v[8 * i + 4]) | ((unsigned)f2bf(v[8 * i + 5]) << 16);
    u.w = (unsigned)f2bf(v[8 * i + 6]) | ((unsigned)f2bf(v[8 * i + 7]) << 16);
    ((uint4*)p)[i] = u;
  }
}

__global__ __launch_bounds__(256) void k_zb(const float* __restrict__ x,
                                            const float* __restrict__ W2,
                                            const float* __restrict__ Ws0,
                                            const float* __restrict__ Ws1,
                                            unsigned short* __restrict__ z0T,
                                            unsigned short* __restrict__ bias0,
                                            unsigned short* __restrict__ bias1) {
  __shared__ __align__(16) float w[3][1024];
  int tid = threadIdx.x;
  for (int i = tid; i < 1024; i += 256) {
    w[0][i] = W2[i]; w[1][i] = Ws0[i]; w[2][i] = Ws1[i];
  }
  __syncthreads();
  int bx = blockIdx.x;
  int b = bx / 96, r = bx % 96, t = r >> 3, mc = r & 7;
  int m = (mc << 8) + tid;
  const float4* xp = (const float4*)(x + (((size_t)(b * 2048 + m)) * 12 + t) * 32);
  float xv[32];
#pragma unroll
  for (int i = 0; i < 8; ++i) {
    float4 v = xp[i];
    xv[4 * i + 0] = v.x; xv[4 * i + 1] = v.y; xv[4 * i + 2] = v.z; xv[4 * i + 3] = v.w;
  }
  float out[32];
  compute_mat(w[0], xv, out);
  unsigned short* zp = z0T + (size_t)b * 786432 + (size_t)(t * 32) * 2048 + m;
#pragma unroll
  for (int d = 0; d < 32; ++d) zp[(size_t)d * 2048] = f2bf(out[d]);
  size_t bb = ((size_t)(b * 2048 + m)) * 384 + t * 32;
  compute_mat(w[1], xv, out);
  store32bf(bias0 + bb, out);
  compute_mat(w[2], xv, out);
  store32bf(bias1 + bb, out);
}

// ---------------- phase C: adj @ z (+bias) MFMA GEMM ----------------

template <int OUT_F32>
__global__ __launch_bounds__(256) void gemm_adj(const unsigned short* __restrict__ adj,
                                                const unsigned short* __restrict__ Bt,
                                                const unsigned short* __restrict__ bias,
                                                void* __restrict__ outp) {
  const int tid = threadIdx.x;
  const int lane = tid & 63;
  const int wid = tid >> 6;
  const int wr = wid >> 1, wc = wid & 1;
  const int c0 = blockIdx.x * 128;
  const int m0 = blockIdx.y * 128;
  const int b = blockIdx.z;

  __shared__ __align__(16) unsigned char smem[32768];

  const unsigned short* aBase = adj + ((size_t)b << 22);
  const unsigned short* bBase = Bt + (size_t)b * 786432;
  const unsigned short* gsrc[8];
  {
    const int rr = tid >> 3, j = tid & 7;
#pragma unroll
    for (int ii = 0; ii < 4; ++ii) {
      int rA = ii * 32 + rr;
      gsrc[ii] = aBase + (size_t)(m0 + rA) * 2048 + ((j ^ (rA & 7)) << 3);
      gsrc[4 + ii] = bBase + (size_t)(c0 + rA) * 2048 + ((j ^ (rA & 7)) << 3);
    }
  }
  int aoff[2][4], boff[2][4];
#pragma unroll
  for (int kk = 0; kk < 2; ++kk) {
#pragma unroll
    for (int f = 0; f < 4; ++f) {
      int c = kk * 4 + (lane >> 4);
      int rA = wr * 64 + f * 16 + (lane & 15);
      aoff[kk][f] = rA * 128 + ((c ^ (rA & 7)) << 4);
      int rB = wc * 64 + f * 16 + (lane & 15);
      boff[kk][f] = 16384 + rB * 128 + ((c ^ (rB & 7)) << 4);
    }
  }

  f32x4 acc[4][4] = {};
  const int ldsW = wid * 1024;

  for (int kt = 0; kt < 32; ++kt) {
#pragma unroll
    for (int ii = 0; ii < 4; ++ii) gload16(gsrc[ii], smem + ii * 4096 + ldsW);
#pragma unroll
    for (int ii = 0; ii < 4; ++ii) gload16(gsrc[4 + ii], smem + 16384 + ii * 4096 + ldsW);
#pragma unroll
    for (int ii = 0; ii < 8; ++ii) gsrc[ii] += 64;
    __syncthreads();
#pragma unroll
    for (int kk = 0; kk < 2; ++kk) {
      bf16x8 af[4], bfv[4];
#pragma unroll
      for (int f = 0; f < 4; ++f) af[f] = *(const bf16x8*)(smem + aoff[kk][f]);
#pragma unroll
      for (int f = 0; f < 4; ++f) bfv[f] = *(const bf16x8*)(smem + boff[kk][f]);
#pragma unroll
      for (int m = 0; m < 4; ++m)
#pragma unroll
        for (int n = 0; n < 4; ++n)
          acc[m][n] = __builtin_amdgcn_mfma_f32_16x16x32_bf16(af[m], bfv[n], acc[m][n], 0, 0, 0);
    }
    __syncthreads();
  }

  const int cl = lane & 15;
  const int r4 = (lane >> 4) << 2;
  const unsigned short* bi = bias + (size_t)b * 786432;
  if (OUT_F32) {
    float* o = (float*)outp + (size_t)b * 786432;
#pragma unroll
    for (int m = 0; m < 4; ++m) {
      int row0 = m0 + wr * 64 + m * 16 + r4;
#pragma unroll
      for (int n = 0; n < 4; ++n) {
        int col = c0 + wc * 64 + n * 16 + cl;
#pragma unroll
        for (int r = 0; r < 4; ++r) {
          int row = row0 + r;
          o[(size_t)row * 384 + col] = acc[m][n][r] + bf2f(bi[(size_t)row * 384 + col]);
        }
      }
    }
  } else {
    unsigned short* o = (unsigned short*)outp + (size_t)b * 786432;
#pragma unroll
    for (int m = 0; m < 4; ++m) {
      int row0 = m0 + wr * 64 + m * 16 + r4;
#pragma unroll
      for (int n = 0; n < 4; ++n) {
        int col = c0 + wc * 64 + n * 16 + cl;
        ushort4 pk;
        pk.x = f2bf(acc[m][n][0] + bf2f(bi[(size_t)(row0 + 0) * 384 + col]));
        pk.y = f2bf(acc[m][n][1] + bf2f(bi[(size_t)(row0 + 1) * 384 + col]));
        pk.z = f2bf(acc[m][n][2] + bf2f(bi[(size_t)(row0 + 2) * 384 + col]));
        pk.w = f2bf(acc[m][n][3] + bf2f(bi[(size_t)(row0 + 3) * 384 + col]));
        *(ushort4*)(o + (size_t)col * 2048 + row0) = pk;
      }
    }
  }
}

// ---------------- launch ----------------

extern "C" void kernel_launch(void* const* d_in, const int* in_sizes, int n_in,
                              void* d_out, int out_size, void* d_ws, size_t ws_size,
                              hipStream_t stream) {
  const float* x = (const float*)d_in[0];
  const float* dis = (const float*)d_in[1];
  const float* K_S = (const float*)d_in[2];
  const float* V_S = (const float*)d_in[3];
  const float* K_T = (const float*)d_in[4];
  const float* V_T = (const float*)d_in[5];
  const float* W_Q0 = (const float*)d_in[6];
  const float* W_QS = (const float*)d_in[7];
  const float* W_QT = (const float*)d_in[8];
  const float* W2 = (const float*)d_in[9];
  const float* W_s0 = (const float*)d_in[10];
  const float* W_s1 = (const float*)d_in[11];

  char* ws = (char*)d_ws;
  float* xmn = (float*)(ws + 0);                             //     24,576 B
  float* qt = (float*)(ws + 24576);                          //      4,096 B
  float* pqs = (float*)(ws + 28672);                         //  2,097,152 B
  float* qs = (float*)(ws + 2125824);                        //      4,096 B
  float* attn = (float*)(ws + 2129920);                      //        512 B
  unsigned short* ets_bf = (unsigned short*)(ws + 2130432);  //  1,048,576 B
  unsigned short* adj = (unsigned short*)(ws + 3179008);     // 134,217,728 B
  unsigned short* z0T = (unsigned short*)(ws + 137396736);   // 25,165,824 B
  unsigned short* z1T = (unsigned short*)(ws + 162562560);   // 25,165,824 B
  unsigned short* bias0 = (unsigned short*)(ws + 187728384); // 25,165,824 B
  unsigned short* bias1 = (unsigned short*)(ws + 212894208); // 25,165,824 B

  k_xmn<<<192, 256, 0, stream>>>(x, xmn);
  k_qs<<<512, 256, 0, stream>>>(x, W_Q0, W_QS, pqs);
  k_qs_reduce<<<16, 256, 0, stream>>>(pqs, qs);
  k_qt<<<16, 384, 0, stream>>>(xmn, W_Q0, W_QT, qt);
  k_attn<<<16, 64, 0, stream>>>(qs, qt, K_T, K_S, attn);
  k_ets<<<128, 256, 0, stream>>>(attn, V_T, V_S, ets_bf);
  k_adj<<<2048, 512, 0, stream>>>(ets_bf, dis, adj);
  k_zb<<<1536, 256, 0, stream>>>(x, W2, W_s0, W_s1, z0T, bias0, bias1);
  dim3 gg(3, 16, 16);
  gemm_adj<0><<<gg, 256, 0, stream>>>(adj, z0T, bias0, (void*)z1T);
  gemm_adj<1><<<gg, 256, 0, stream>>>(adj, z1T, bias1, d_out);
}

// Round 4
// 435.566 us; speedup vs baseline: 2.9064x; 1.0850x over previous
//
#include <hip/hip_runtime.h>

typedef __bf16 bf16x8 __attribute__((ext_vector_type(8)));
typedef float f32x4 __attribute__((ext_vector_type(4)));

__device__ __forceinline__ unsigned short f2bf(float f) {
  unsigned u = __builtin_bit_cast(unsigned, f);
  u += 0x7fffu + ((u >> 16) & 1u);
  return (unsigned short)(u >> 16);
}
__device__ __forceinline__ float bf2f(unsigned short h) {
  unsigned u = ((unsigned)h) << 16;
  return __builtin_bit_cast(float, u);
}
__device__ __forceinline__ void gload16(const void* g, void* l) {
  __builtin_amdgcn_global_load_lds((const __attribute__((address_space(1))) void*)g,
                                   (__attribute__((address_space(3))) void*)l, 16, 0, 0);
}

// ---------------- phase A ----------------

// xmn[b,t,k] = mean_n x[b,:,t,k]
__global__ __launch_bounds__(256) void k_xmn(const float* __restrict__ x, float* __restrict__ xmn) {
  int b = blockIdx.x / 12, t = blockIdx.x % 12;
  int k = threadIdx.x & 31, sl = threadIdx.x >> 5;
  const float* xp = x + (size_t)b * 786432 + (size_t)t * 32 + k;
  float s = 0.f;
  for (int i = 0; i < 256; ++i) {
    int n = (sl << 8) + i;
    s += xp[(size_t)n * 384];
  }
  __shared__ float red[8][32];
  red[sl][k] = s;
  __syncthreads();
  if (threadIdx.x < 32) {
    float tot = 0.f;
#pragma unroll
    for (int j = 0; j < 8; ++j) tot += red[j][threadIdx.x];
    xmn[(b * 12 + t) * 32 + threadIdx.x] = tot * (1.0f / 2048.0f);
  }
}

// Fused: per block (4 n-values): mean_t(x) -> @W_Q0 -> contract with W_QS rows
__global__ __launch_bounds__(256) void k_qs(const float* __restrict__ x,
                                            const float* __restrict__ W_Q0,
                                            const float* __restrict__ W_QS,
                                            float* __restrict__ pqs) {
  __shared__ __align__(16) float w0[1024];
  __shared__ float lm[2048];
  __shared__ float lq[2048];
  __shared__ float red[4][16][64];
  int tid = threadIdx.x;
#pragma unroll
  for (int i = 0; i < 4; ++i) w0[tid + i * 256] = W_Q0[tid + i * 256];
  int n0 = blockIdx.x * 4;
#pragma unroll
  for (int j = 0; j < 8; ++j) {
    int i = tid + j * 256;
    int b = i >> 7, r = i & 127;
    int n = n0 + (r >> 5), k = r & 31;
    const float* xp = x + ((size_t)(b * 2048 + n) * 12) * 32 + k;
    float s = 0.f;
#pragma unroll
    for (int t = 0; t < 12; ++t) s += xp[t * 32];
    lm[i] = s * (1.0f / 12.0f);
  }
  __syncthreads();
#pragma unroll
  for (int j = 0; j < 8; ++j) {
    int i = tid + j * 256;
    int br = i >> 5, q = i & 31;
    const float* mrow = &lm[br * 32];
    float a = 0.f;
#pragma unroll
    for (int k = 0; k < 32; ++k) a += mrow[k] * w0[k * 32 + q];
    lq[i] = a;
  }
  __syncthreads();
  int lane = tid & 63, wid = tid >> 6;
  float acc[16];
#pragma unroll
  for (int b = 0; b < 16; ++b) acc[b] = 0.f;
  for (int rl = 0; rl < 32; ++rl) {
    int r = wid * 32 + rl;
    float wv = W_QS[(size_t)(n0 * 32 + r) * 64 + lane];
#pragma unroll
    for (int b = 0; b < 16; ++b) acc[b] += lq[b * 128 + r] * wv;
  }
#pragma unroll
  for (int b = 0; b < 16; ++b) red[wid][b][lane] = acc[b];
  __syncthreads();
#pragma unroll
  for (int it = 0; it < 4; ++it) {
    int idx = tid + it * 256;
    float s = red[0][idx >> 6][idx & 63] + red[1][idx >> 6][idx & 63] +
              red[2][idx >> 6][idx & 63] + red[3][idx >> 6][idx & 63];
    pqs[(size_t)blockIdx.x * 1024 + idx] = s;
  }
}

// Fused tail: qs-reduce + qt + attn + ets  (one block per batch b)
__global__ __launch_bounds__(256) void k_post(const float* __restrict__ pqs,
                                              const float* __restrict__ xmn,
                                              const float* __restrict__ W_Q0,
                                              const float* __restrict__ W_QT,
                                              const float* __restrict__ K_T,
                                              const float* __restrict__ K_S,
                                              const float* __restrict__ V_T,
                                              const float* __restrict__ V_S,
                                              unsigned short* __restrict__ ets_bf) {
  const int b = blockIdx.x, tid = threadIdx.x;
  __shared__ float red[4][64];
  __shared__ float qs_s[64];
  __shared__ float qt_s[64];
  __shared__ float xp[384];
  __shared__ float at_s[8];

  // qs reduce
  {
    float s = 0.f;
    for (int c = tid >> 6; c < 512; c += 4) s += pqs[(size_t)c * 1024 + b * 64 + (tid & 63)];
    red[tid >> 6][tid & 63] = s;
  }
  // xp[384] = (xmn[b] @ W_Q0) flattened
  for (int i = tid; i < 384; i += 256) {
    int t = i >> 5, q = i & 31;
    float a = 0.f;
#pragma unroll
    for (int k = 0; k < 32; ++k) a += xmn[(b * 12 + t) * 32 + k] * W_Q0[k * 32 + q];
    xp[i] = a;
  }
  __syncthreads();
  if (tid < 64) qs_s[tid] = red[0][tid] + red[1][tid] + red[2][tid] + red[3][tid];
  __syncthreads();
  if (tid < 64) {
    float q = 0.f;
    for (int i = 0; i < 384; ++i) q += xp[i] * W_QT[i * 64 + tid];
    qt_s[tid] = q;
  }
  __syncthreads();
  if (tid < 64) {
    int lane = tid;
    float qsv = qs_s[lane], qtv = qt_s[lane];
    float lt[4], ls[4];
#pragma unroll
    for (int h = 0; h < 4; ++h) {
      float p = qtv * K_T[h * 64 + lane];
#pragma unroll
      for (int off = 32; off > 0; off >>= 1) p += __shfl_xor(p, off);
      lt[h] = p;
      float p2 = qsv * K_S[h * 64 + lane];
#pragma unroll
      for (int off = 32; off > 0; off >>= 1) p2 += __shfl_xor(p2, off);
      ls[h] = p2;
    }
    if (lane == 0) {
      const float scale = 0.125f;
      float mt = fmaxf(fmaxf(lt[0], lt[1]), fmaxf(lt[2], lt[3]));
      float ms = fmaxf(fmaxf(ls[0], ls[1]), fmaxf(ls[2], ls[3]));
      float et[4], es[4], st = 0.f, ss = 0.f;
#pragma unroll
      for (int h = 0; h < 4; ++h) {
        et[h] = __expf((lt[h] - mt) * scale); st += et[h];
        es[h] = __expf((ls[h] - ms) * scale); ss += es[h];
      }
#pragma unroll
      for (int h = 0; h < 4; ++h) {
        at_s[h] = et[h] / st;
        at_s[4 + h] = es[h] / ss;
      }
    }
  }
  __syncthreads();
  float a0 = at_s[0], a1 = at_s[1], a2 = at_s[2], a3 = at_s[3];
  float s0 = at_s[4], s1 = at_s[5], s2 = at_s[6], s3 = at_s[7];
  for (int n = tid; n < 2048; n += 256) {
    float v[10];
#pragma unroll
    for (int c = 0; c < 10; ++c) {
      int o = n * 10 + c;
      v[c] = a0 * V_T[o] + a1 * V_T[20480 + o] + a2 * V_T[40960 + o] + a3 * V_T[61440 + o] +
             s0 * V_S[o] + s1 * V_S[20480 + o] + s2 * V_S[40960 + o] + s3 * V_S[61440 + o];
    }
    uint4 lo, hi;
    lo.x = (unsigned)f2bf(v[0]) | ((unsigned)f2bf(v[1]) << 16);
    lo.y = (unsigned)f2bf(v[2]) | ((unsigned)f2bf(v[3]) << 16);
    lo.z = (unsigned)f2bf(v[4]) | ((unsigned)f2bf(v[5]) << 16);
    lo.w = (unsigned)f2bf(v[6]) | ((unsigned)f2bf(v[7]) << 16);
    hi.x = (unsigned)f2bf(v[8]) | ((unsigned)f2bf(v[9]) << 16);
    hi.y = 0; hi.z = 0; hi.w = 0;
    size_t idx = (size_t)b * 2048 + n;
    *(uint4*)(ets_bf + idx * 16) = lo;
    *(uint4*)(ets_bf + idx * 16 + 8) = hi;
  }
}

// ---------------- phase B: MFMA adjacency + row softmax -> bf16 ----------------

__global__ __launch_bounds__(512, 4) void k_adj(const unsigned short* __restrict__ ets_bf,
                                                const float* __restrict__ dis,
                                                unsigned short* __restrict__ adj) {
  __shared__ __align__(16) unsigned char Bsh[65536];
  __shared__ float st_max[8][16];
  __shared__ float st_sum[8][16];
  __shared__ float rowmax_s[16];
  __shared__ float rowinv_s[16];

  const int tid = threadIdx.x;
  const int lane = tid & 63;
  const int w = tid >> 6;
  const int cl = lane & 15;
  const int g = lane >> 4;
  const int b = blockIdx.x >> 7;
  const int n0 = (blockIdx.x & 127) << 4;

  const unsigned char* gsrc = (const unsigned char*)(ets_bf + (size_t)b * 32768);
#pragma unroll
  for (int it = 0; it < 8; ++it)
    gload16(gsrc + it * 8192 + tid * 16, Bsh + it * 8192 + (w << 10));
  __syncthreads();

  uint4 araw = *(const uint4*)(ets_bf + ((size_t)b * 2048 + n0 + cl) * 16 + (g & 1) * 8);
  if (g >= 2) { araw.x = 0; araw.y = 0; araw.z = 0; araw.w = 0; }
  bf16x8 afrag = __builtin_bit_cast(bf16x8, araw);

  f32x4 acc[16];
  const int cbase = (w << 8) + cl;
#pragma unroll
  for (int n = 0; n < 16; ++n) {
    uint4 braw = *(const uint4*)(Bsh + (size_t)(cbase + n * 16) * 32 + (g & 1) * 16);
    if (g >= 2) { braw.x = 0; braw.y = 0; braw.z = 0; braw.w = 0; }
    bf16x8 bfrag = __builtin_bit_cast(bf16x8, braw);
    acc[n] = __builtin_amdgcn_mfma_f32_16x16x32_bf16(afrag, bfrag, (f32x4){0.f, 0.f, 0.f, 0.f},
                                                     0, 0, 0);
  }

  float mx[4] = {-1e30f, -1e30f, -1e30f, -1e30f};
  const float* dbase = dis + (size_t)(n0 + g * 4) * 2048 + (w << 8) + cl;
#pragma unroll
  for (int n = 0; n < 16; ++n) {
#pragma unroll
    for (int j = 0; j < 4; ++j) {
      float s = fmaxf(acc[n][j] + dbase[(size_t)j * 2048 + n * 16], 0.f);
      acc[n][j] = s;
      mx[j] = fmaxf(mx[j], s);
    }
  }
#pragma unroll
  for (int j = 0; j < 4; ++j) {
    mx[j] = fmaxf(mx[j], __shfl_xor(mx[j], 1));
    mx[j] = fmaxf(mx[j], __shfl_xor(mx[j], 2));
    mx[j] = fmaxf(mx[j], __shfl_xor(mx[j], 4));
    mx[j] = fmaxf(mx[j], __shfl_xor(mx[j], 8));
  }
  if (cl == 0) {
#pragma unroll
    for (int j = 0; j < 4; ++j) st_max[w][g * 4 + j] = mx[j];
  }
  __syncthreads();
  if (tid < 16) {
    float m = st_max[0][tid];
#pragma unroll
    for (int ww = 1; ww < 8; ++ww) m = fmaxf(m, st_max[ww][tid]);
    rowmax_s[tid] = m;
  }
  __syncthreads();

  float rm[4], sm[4] = {0.f, 0.f, 0.f, 0.f};
#pragma unroll
  for (int j = 0; j < 4; ++j) rm[j] = rowmax_s[g * 4 + j];
#pragma unroll
  for (int n = 0; n < 16; ++n) {
#pragma unroll
    for (int j = 0; j < 4; ++j) {
      float e = __expf(acc[n][j] - rm[j]);
      acc[n][j] = e;
      sm[j] += e;
    }
  }
#pragma unroll
  for (int j = 0; j < 4; ++j) {
    sm[j] += __shfl_xor(sm[j], 1);
    sm[j] += __shfl_xor(sm[j], 2);
    sm[j] += __shfl_xor(sm[j], 4);
    sm[j] += __shfl_xor(sm[j], 8);
  }
  if (cl == 0) {
#pragma unroll
    for (int j = 0; j < 4; ++j) st_sum[w][g * 4 + j] = sm[j];
  }
  __syncthreads();
  if (tid < 16) {
    float s = st_sum[0][tid];
#pragma unroll
    for (int ww = 1; ww < 8; ++ww) s += st_sum[ww][tid];
    rowinv_s[tid] = 1.0f / s;
  }
  __syncthreads();

  unsigned short* Tw = (unsigned short*)Bsh + (w << 12);
  float inv[4];
#pragma unroll
  for (int j = 0; j < 4; ++j) inv[j] = rowinv_s[g * 4 + j];
#pragma unroll
  for (int n = 0; n < 16; ++n) {
#pragma unroll
    for (int j = 0; j < 4; ++j)
      Tw[(g * 4 + j) * 256 + n * 16 + cl] = f2bf(acc[n][j] * inv[j]);
  }
  __syncthreads();

  unsigned short* obase = adj + ((size_t)b * 2048 + n0) * 2048 + (w << 8);
#pragma unroll
  for (int r = 0; r < 16; ++r) {
    uint2 v = *(const uint2*)(Tw + r * 256 + lane * 4);
    *(uint2*)(obase + (size_t)r * 2048 + lane * 4) = v;
  }
}

// ---------------- phase C producers ----------------

__device__ __forceinline__ void compute_mat(const float* w, const float* xv, float* out) {
  float4 a[8];
#pragma unroll
  for (int i = 0; i < 8; ++i) a[i] = make_float4(0.f, 0.f, 0.f, 0.f);
#pragma unroll
  for (int k = 0; k < 32; ++k) {
    float xk = xv[k];
#pragma unroll
    for (int d4 = 0; d4 < 8; ++d4) {
      float4 wv = ((const float4*)(w + k * 32))[d4];
      a[d4].x += xk * wv.x; a[d4].y += xk * wv.y; a[d4].z += xk * wv.z; a[d4].w += xk * wv.w;
    }
  }
#pragma unroll
  for (int d4 = 0; d4 < 8; ++d4) {
    out[4 * d4 + 0] = a[d4].x; out[4 * d4 + 1] = a[d4].y;
    out[4 * d4 + 2] = a[d4].z; out[4 * d4 + 3] = a[d4].w;
  }
}

__device__ __forceinline__ void store32bf(unsigned short* p, const float* v) {
#pragma unroll
  for (int i = 0; i < 4; ++i) {
    uint4 u;
    u.x = (unsigned)f2bf(v[8 * i + 0]) | ((unsigned)f2bf(v[8 * i + 1]) << 16);
    u.y = (unsigned)f2bf(v[8 * i + 2]) | ((unsigned)f2bf(v[8 * i + 3]) << 16);
    u.z = (unsigned)f2bf(v[8 * i + 4]) | ((unsigned)f2bf(v[8 * i + 5]) << 16);
    u.w = (unsigned)f2bf(v[8 * i + 6]) | ((unsigned)f2bf(v[8 * i + 7]) << 16);
    ((uint4*)p)[i] = u;
  }
}

__global__ __launch_bounds__(256) void k_zb(const float* __restrict__ x,
                                            const float* __restrict__ W2,
                                            const float* __restrict__ Ws0,
                                            const float* __restrict__ Ws1,
                                            unsigned short* __restrict__ z0T,
                                            unsigned short* __restrict__ bias0,
                                            unsigned short* __restrict__ bias1) {
  __shared__ __align__(16) float w[3][1024];
  int tid = threadIdx.x;
  for (int i = tid; i < 1024; i += 256) {
    w[0][i] = W2[i]; w[1][i] = Ws0[i]; w[2][i] = Ws1[i];
  }
  __syncthreads();
  int bx = blockIdx.x;
  int b = bx / 96, r = bx % 96, t = r >> 3, mc = r & 7;
  int m = (mc << 8) + tid;
  const float4* xp = (const float4*)(x + (((size_t)(b * 2048 + m)) * 12 + t) * 32);
  float xv[32];
#pragma unroll
  for (int i = 0; i < 8; ++i) {
    float4 v = xp[i];
    xv[4 * i + 0] = v.x; xv[4 * i + 1] = v.y; xv[4 * i + 2] = v.z; xv[4 * i + 3] = v.w;
  }
  float out[32];
  compute_mat(w[0], xv, out);
  unsigned short* zp = z0T + (size_t)b * 786432 + (size_t)(t * 32) * 2048 + m;
#pragma unroll
  for (int d = 0; d < 32; ++d) zp[(size_t)d * 2048] = f2bf(out[d]);
  size_t bb = ((size_t)(b * 2048 + m)) * 384 + t * 32;
  compute_mat(w[1], xv, out);
  store32bf(bias0 + bb, out);
  compute_mat(w[2], xv, out);
  store32bf(bias1 + bb, out);
}

// ---------------- phase C: adj @ z (+bias) MFMA GEMM, double-buffered ----------------

template <int OUT_F32>
__global__ __launch_bounds__(256) void gemm_adj(const unsigned short* __restrict__ adj,
                                                const unsigned short* __restrict__ Bt,
                                                const unsigned short* __restrict__ bias,
                                                void* __restrict__ outp) {
  const int tid = threadIdx.x;
  const int lane = tid & 63;
  const int wid = tid >> 6;
  const int wr = wid >> 1, wc = wid & 1;
  // XCD-bijective swizzle: 768 blocks = 8 XCDs x 96; same-A trios + same-batch stay co-XCD
  const int orig = blockIdx.x;
  const int wg = (orig & 7) * 96 + (orig >> 3);
  const int c0 = (wg % 3) * 128;
  const int m0 = ((wg / 3) & 15) * 128;
  const int b = wg / 48;

  __shared__ __align__(16) unsigned char smem[65536];  // 2 x (A 16K | B 16K)

  const unsigned short* aBase = adj + ((size_t)b << 22);
  const unsigned short* bBase = Bt + (size_t)b * 786432;
  const unsigned short* gsrc[8];
  {
    const int rr = tid >> 3, j = tid & 7;
#pragma unroll
    for (int ii = 0; ii < 4; ++ii) {
      int rA = ii * 32 + rr;
      gsrc[ii] = aBase + (size_t)(m0 + rA) * 2048 + ((j ^ (rA & 7)) << 3);
      gsrc[4 + ii] = bBase + (size_t)(c0 + rA) * 2048 + ((j ^ (rA & 7)) << 3);
    }
  }
  int aoff[2][4], boff[2][4];
#pragma unroll
  for (int kk = 0; kk < 2; ++kk) {
#pragma unroll
    for (int f = 0; f < 4; ++f) {
      int c = kk * 4 + (lane >> 4);
      int rA = wr * 64 + f * 16 + (lane & 15);
      aoff[kk][f] = rA * 128 + ((c ^ (rA & 7)) << 4);
      int rB = wc * 64 + f * 16 + (lane & 15);
      boff[kk][f] = 16384 + rB * 128 + ((c ^ (rB & 7)) << 4);
    }
  }

  f32x4 acc[4][4] = {};
  const int ldsW = wid * 1024;

  // prologue: stage tile 0 into buffer 0
#pragma unroll
  for (int ii = 0; ii < 4; ++ii) gload16(gsrc[ii], smem + ii * 4096 + ldsW);
#pragma unroll
  for (int ii = 0; ii < 4; ++ii) gload16(gsrc[4 + ii], smem + 16384 + ii * 4096 + ldsW);
  __syncthreads();

  int cur = 0;
  for (int kt = 0; kt < 32; ++kt) {
    const int nxt = cur ^ 32768;
    if (kt < 31) {  // prefetch tile kt+1 into the other buffer (flies during MFMA)
#pragma unroll
      for (int ii = 0; ii < 4; ++ii)
        gload16(gsrc[ii] + (kt + 1) * 64, smem + nxt + ii * 4096 + ldsW);
#pragma unroll
      for (int ii = 0; ii < 4; ++ii)
        gload16(gsrc[4 + ii] + (kt + 1) * 64, smem + nxt + 16384 + ii * 4096 + ldsW);
    }
#pragma unroll
    for (int kk = 0; kk < 2; ++kk) {
      bf16x8 af[4], bfv[4];
#pragma unroll
      for (int f = 0; f < 4; ++f) af[f] = *(const bf16x8*)(smem + cur + aoff[kk][f]);
#pragma unroll
      for (int f = 0; f < 4; ++f) bfv[f] = *(const bf16x8*)(smem + cur + boff[kk][f]);
#pragma unroll
      for (int m = 0; m < 4; ++m)
#pragma unroll
        for (int n = 0; n < 4; ++n)
          acc[m][n] = __builtin_amdgcn_mfma_f32_16x16x32_bf16(af[m], bfv[n], acc[m][n], 0, 0, 0);
    }
    __syncthreads();  // drains prefetch vmcnt + lgkm; one barrier per K-step
    cur = nxt;
  }

  const int cl = lane & 15;
  const int r4 = (lane >> 4) << 2;
  const unsigned short* bi = bias + (size_t)b * 786432;
  if (OUT_F32) {
    float* o = (float*)outp + (size_t)b * 786432;
#pragma unroll
    for (int m = 0; m < 4; ++m) {
      int row0 = m0 + wr * 64 + m * 16 + r4;
#pragma unroll
      for (int n = 0; n < 4; ++n) {
        int col = c0 + wc * 64 + n * 16 + cl;
#pragma unroll
        for (int r = 0; r < 4; ++r) {
          int row = row0 + r;
          o[(size_t)row * 384 + col] = acc[m][n][r] + bf2f(bi[(size_t)row * 384 + col]);
        }
      }
    }
  } else {
    unsigned short* o = (unsigned short*)outp + (size_t)b * 786432;
#pragma unroll
    for (int m = 0; m < 4; ++m) {
      int row0 = m0 + wr * 64 + m * 16 + r4;
#pragma unroll
      for (int n = 0; n < 4; ++n) {
        int col = c0 + wc * 64 + n * 16 + cl;
        ushort4 pk;
        pk.x = f2bf(acc[m][n][0] + bf2f(bi[(size_t)(row0 + 0) * 384 + col]));
        pk.y = f2bf(acc[m][n][1] + bf2f(bi[(size_t)(row0 + 1) * 384 + col]));
        pk.z = f2bf(acc[m][n][2] + bf2f(bi[(size_t)(row0 + 2) * 384 + col]));
        pk.w = f2bf(acc[m][n][3] + bf2f(bi[(size_t)(row0 + 3) * 384 + col]));
        *(ushort4*)(o + (size_t)col * 2048 + row0) = pk;
      }
    }
  }
}

// ---------------- launch ----------------

extern "C" void kernel_launch(void* const* d_in, const int* in_sizes, int n_in,
                              void* d_out, int out_size, void* d_ws, size_t ws_size,
                              hipStream_t stream) {
  const float* x = (const float*)d_in[0];
  const float* dis = (const float*)d_in[1];
  const float* K_S = (const float*)d_in[2];
  const float* V_S = (const float*)d_in[3];
  const float* K_T = (const float*)d_in[4];
  const float* V_T = (const float*)d_in[5];
  const float* W_Q0 = (const float*)d_in[6];
  const float* W_QS = (const float*)d_in[7];
  const float* W_QT = (const float*)d_in[8];
  const float* W2 = (const float*)d_in[9];
  const float* W_s0 = (const float*)d_in[10];
  const float* W_s1 = (const float*)d_in[11];

  char* ws = (char*)d_ws;
  float* xmn = (float*)(ws + 0);                             //     24,576 B
  float* pqs = (float*)(ws + 28672);                         //  2,097,152 B
  unsigned short* ets_bf = (unsigned short*)(ws + 2130432);  //  1,048,576 B
  unsigned short* adj = (unsigned short*)(ws + 3179008);     // 134,217,728 B
  unsigned short* z0T = (unsigned short*)(ws + 137396736);   // 25,165,824 B
  unsigned short* z1T = (unsigned short*)(ws + 162562560);   // 25,165,824 B
  unsigned short* bias0 = (unsigned short*)(ws + 187728384); // 25,165,824 B
  unsigned short* bias1 = (unsigned short*)(ws + 212894208); // 25,165,824 B

  k_xmn<<<192, 256, 0, stream>>>(x, xmn);
  k_qs<<<512, 256, 0, stream>>>(x, W_Q0, W_QS, pqs);
  k_post<<<16, 256, 0, stream>>>(pqs, xmn, W_Q0, W_QT, K_T, K_S, V_T, V_S, ets_bf);
  k_adj<<<2048, 512, 0, stream>>>(ets_bf, dis, adj);
  k_zb<<<1536, 256, 0, stream>>>(x, W2, W_s0, W_s1, z0T, bias0, bias1);
  gemm_adj<0><<<768, 256, 0, stream>>>(adj, z0T, bias0, (void*)z1T);
  gemm_adj<1><<<768, 256, 0, stream>>>(adj, z1T, bias1, d_out);
}

// Round 5
// 402.816 us; speedup vs baseline: 3.1427x; 1.0813x over previous
//
#include <hip/hip_runtime.h>

typedef __bf16 bf16x8 __attribute__((ext_vector_type(8)));
typedef float f32x4 __attribute__((ext_vector_type(4)));

__device__ __forceinline__ unsigned short f2bf(float f) {
  unsigned u = __builtin_bit_cast(unsigned, f);
  u += 0x7fffu + ((u >> 16) & 1u);
  return (unsigned short)(u >> 16);
}
__device__ __forceinline__ float bf2f(unsigned short h) {
  unsigned u = ((unsigned)h) << 16;
  return __builtin_bit_cast(float, u);
}
__device__ __forceinline__ void gload16(const void* g, void* l) {
  __builtin_amdgcn_global_load_lds((const __attribute__((address_space(1))) void*)g,
                                   (__attribute__((address_space(3))) void*)l, 16, 0, 0);
}

// ---------------- phase A ----------------

// xmn[b,t,k] = mean_n x[b,:,t,k]
__global__ __launch_bounds__(256) void k_xmn(const float* __restrict__ x, float* __restrict__ xmn) {
  int b = blockIdx.x / 12, t = blockIdx.x % 12;
  int k = threadIdx.x & 31, sl = threadIdx.x >> 5;
  const float* xp = x + (size_t)b * 786432 + (size_t)t * 32 + k;
  float s = 0.f;
  for (int i = 0; i < 256; ++i) {
    int n = (sl << 8) + i;
    s += xp[(size_t)n * 384];
  }
  __shared__ float red[8][32];
  red[sl][k] = s;
  __syncthreads();
  if (threadIdx.x < 32) {
    float tot = 0.f;
#pragma unroll
    for (int j = 0; j < 8; ++j) tot += red[j][threadIdx.x];
    xmn[(b * 12 + t) * 32 + threadIdx.x] = tot * (1.0f / 2048.0f);
  }
}

// Fused: per block (4 n-values): mean_t(x) -> @W_Q0 -> contract with W_QS rows
__global__ __launch_bounds__(256) void k_qs(const float* __restrict__ x,
                                            const float* __restrict__ W_Q0,
                                            const float* __restrict__ W_QS,
                                            float* __restrict__ pqs) {
  __shared__ __align__(16) float w0[1024];
  __shared__ float lm[2048];
  __shared__ float lq[2048];
  __shared__ float red[4][16][64];
  int tid = threadIdx.x;
#pragma unroll
  for (int i = 0; i < 4; ++i) w0[tid + i * 256] = W_Q0[tid + i * 256];
  int n0 = blockIdx.x * 4;
#pragma unroll
  for (int j = 0; j < 8; ++j) {
    int i = tid + j * 256;
    int b = i >> 7, r = i & 127;
    int n = n0 + (r >> 5), k = r & 31;
    const float* xp = x + ((size_t)(b * 2048 + n) * 12) * 32 + k;
    float s = 0.f;
#pragma unroll
    for (int t = 0; t < 12; ++t) s += xp[t * 32];
    lm[i] = s * (1.0f / 12.0f);
  }
  __syncthreads();
#pragma unroll
  for (int j = 0; j < 8; ++j) {
    int i = tid + j * 256;
    int br = i >> 5, q = i & 31;
    const float* mrow = &lm[br * 32];
    float a = 0.f;
#pragma unroll
    for (int k = 0; k < 32; ++k) a += mrow[k] * w0[k * 32 + q];
    lq[i] = a;
  }
  __syncthreads();
  int lane = tid & 63, wid = tid >> 6;
  float acc[16];
#pragma unroll
  for (int b = 0; b < 16; ++b) acc[b] = 0.f;
  for (int rl = 0; rl < 32; ++rl) {
    int r = wid * 32 + rl;
    float wv = W_QS[(size_t)(n0 * 32 + r) * 64 + lane];
#pragma unroll
    for (int b = 0; b < 16; ++b) acc[b] += lq[b * 128 + r] * wv;
  }
#pragma unroll
  for (int b = 0; b < 16; ++b) red[wid][b][lane] = acc[b];
  __syncthreads();
#pragma unroll
  for (int it = 0; it < 4; ++it) {
    int idx = tid + it * 256;
    float s = red[0][idx >> 6][idx & 63] + red[1][idx >> 6][idx & 63] +
              red[2][idx >> 6][idx & 63] + red[3][idx >> 6][idx & 63];
    pqs[(size_t)blockIdx.x * 1024 + idx] = s;
  }
}

// Fused tail: qs-reduce + qt + attn + ets  (one block per batch b)
__global__ __launch_bounds__(256) void k_post(const float* __restrict__ pqs,
                                              const float* __restrict__ xmn,
                                              const float* __restrict__ W_Q0,
                                              const float* __restrict__ W_QT,
                                              const float* __restrict__ K_T,
                                              const float* __restrict__ K_S,
                                              const float* __restrict__ V_T,
                                              const float* __restrict__ V_S,
                                              unsigned short* __restrict__ ets_bf) {
  const int b = blockIdx.x, tid = threadIdx.x;
  __shared__ float red[4][64];
  __shared__ float qs_s[64];
  __shared__ float qt_s[64];
  __shared__ float xp[384];
  __shared__ float at_s[8];

  {
    float s = 0.f;
    for (int c = tid >> 6; c < 512; c += 4) s += pqs[(size_t)c * 1024 + b * 64 + (tid & 63)];
    red[tid >> 6][tid & 63] = s;
  }
  for (int i = tid; i < 384; i += 256) {
    int t = i >> 5, q = i & 31;
    float a = 0.f;
#pragma unroll
    for (int k = 0; k < 32; ++k) a += xmn[(b * 12 + t) * 32 + k] * W_Q0[k * 32 + q];
    xp[i] = a;
  }
  __syncthreads();
  if (tid < 64) qs_s[tid] = red[0][tid] + red[1][tid] + red[2][tid] + red[3][tid];
  __syncthreads();
  if (tid < 64) {
    float q = 0.f;
    for (int i = 0; i < 384; ++i) q += xp[i] * W_QT[i * 64 + tid];
    qt_s[tid] = q;
  }
  __syncthreads();
  if (tid < 64) {
    int lane = tid;
    float qsv = qs_s[lane], qtv = qt_s[lane];
    float lt[4], ls[4];
#pragma unroll
    for (int h = 0; h < 4; ++h) {
      float p = qtv * K_T[h * 64 + lane];
#pragma unroll
      for (int off = 32; off > 0; off >>= 1) p += __shfl_xor(p, off);
      lt[h] = p;
      float p2 = qsv * K_S[h * 64 + lane];
#pragma unroll
      for (int off = 32; off > 0; off >>= 1) p2 += __shfl_xor(p2, off);
      ls[h] = p2;
    }
    if (lane == 0) {
      const float scale = 0.125f;
      float mt = fmaxf(fmaxf(lt[0], lt[1]), fmaxf(lt[2], lt[3]));
      float ms = fmaxf(fmaxf(ls[0], ls[1]), fmaxf(ls[2], ls[3]));
      float et[4], es[4], st = 0.f, ss = 0.f;
#pragma unroll
      for (int h = 0; h < 4; ++h) {
        et[h] = __expf((lt[h] - mt) * scale); st += et[h];
        es[h] = __expf((ls[h] - ms) * scale); ss += es[h];
      }
#pragma unroll
      for (int h = 0; h < 4; ++h) {
        at_s[h] = et[h] / st;
        at_s[4 + h] = es[h] / ss;
      }
    }
  }
  __syncthreads();
  float a0 = at_s[0], a1 = at_s[1], a2 = at_s[2], a3 = at_s[3];
  float s0 = at_s[4], s1 = at_s[5], s2 = at_s[6], s3 = at_s[7];
  for (int n = tid; n < 2048; n += 256) {
    float v[10];
#pragma unroll
    for (int c = 0; c < 10; ++c) {
      int o = n * 10 + c;
      v[c] = a0 * V_T[o] + a1 * V_T[20480 + o] + a2 * V_T[40960 + o] + a3 * V_T[61440 + o] +
             s0 * V_S[o] + s1 * V_S[20480 + o] + s2 * V_S[40960 + o] + s3 * V_S[61440 + o];
    }
    uint4 lo, hi;
    lo.x = (unsigned)f2bf(v[0]) | ((unsigned)f2bf(v[1]) << 16);
    lo.y = (unsigned)f2bf(v[2]) | ((unsigned)f2bf(v[3]) << 16);
    lo.z = (unsigned)f2bf(v[4]) | ((unsigned)f2bf(v[5]) << 16);
    lo.w = (unsigned)f2bf(v[6]) | ((unsigned)f2bf(v[7]) << 16);
    hi.x = (unsigned)f2bf(v[8]) | ((unsigned)f2bf(v[9]) << 16);
    hi.y = 0; hi.z = 0; hi.w = 0;
    size_t idx = (size_t)b * 2048 + n;
    *(uint4*)(ets_bf + idx * 16) = lo;
    *(uint4*)(ets_bf + idx * 16 + 8) = hi;
  }
}

// ---------------- phase B: MFMA adjacency + row softmax -> bf16 ----------------

__global__ __launch_bounds__(512, 4) void k_adj(const unsigned short* __restrict__ ets_bf,
                                                const float* __restrict__ dis,
                                                unsigned short* __restrict__ adj) {
  __shared__ __align__(16) unsigned char Bsh[65536];
  __shared__ float st_max[8][16];
  __shared__ float st_sum[8][16];
  __shared__ float rowmax_s[16];
  __shared__ float rowinv_s[16];

  const int tid = threadIdx.x;
  const int lane = tid & 63;
  const int w = tid >> 6;
  const int cl = lane & 15;
  const int g = lane >> 4;
  const int b = blockIdx.x >> 7;
  const int n0 = (blockIdx.x & 127) << 4;

  const unsigned char* gsrc = (const unsigned char*)(ets_bf + (size_t)b * 32768);
#pragma unroll
  for (int it = 0; it < 8; ++it)
    gload16(gsrc + it * 8192 + tid * 16, Bsh + it * 8192 + (w << 10));
  __syncthreads();

  uint4 araw = *(const uint4*)(ets_bf + ((size_t)b * 2048 + n0 + cl) * 16 + (g & 1) * 8);
  if (g >= 2) { araw.x = 0; araw.y = 0; araw.z = 0; araw.w = 0; }
  bf16x8 afrag = __builtin_bit_cast(bf16x8, araw);

  f32x4 acc[16];
  const int cbase = (w << 8) + cl;
#pragma unroll
  for (int n = 0; n < 16; ++n) {
    uint4 braw = *(const uint4*)(Bsh + (size_t)(cbase + n * 16) * 32 + (g & 1) * 16);
    if (g >= 2) { braw.x = 0; braw.y = 0; braw.z = 0; braw.w = 0; }
    bf16x8 bfrag = __builtin_bit_cast(bf16x8, braw);
    acc[n] = __builtin_amdgcn_mfma_f32_16x16x32_bf16(afrag, bfrag, (f32x4){0.f, 0.f, 0.f, 0.f},
                                                     0, 0, 0);
  }

  float mx[4] = {-1e30f, -1e30f, -1e30f, -1e30f};
  const float* dbase = dis + (size_t)(n0 + g * 4) * 2048 + (w << 8) + cl;
#pragma unroll
  for (int n = 0; n < 16; ++n) {
#pragma unroll
    for (int j = 0; j < 4; ++j) {
      float s = fmaxf(acc[n][j] + dbase[(size_t)j * 2048 + n * 16], 0.f);
      acc[n][j] = s;
      mx[j] = fmaxf(mx[j], s);
    }
  }
#pragma unroll
  for (int j = 0; j < 4; ++j) {
    mx[j] = fmaxf(mx[j], __shfl_xor(mx[j], 1));
    mx[j] = fmaxf(mx[j], __shfl_xor(mx[j], 2));
    mx[j] = fmaxf(mx[j], __shfl_xor(mx[j], 4));
    mx[j] = fmaxf(mx[j], __shfl_xor(mx[j], 8));
  }
  if (cl == 0) {
#pragma unroll
    for (int j = 0; j < 4; ++j) st_max[w][g * 4 + j] = mx[j];
  }
  __syncthreads();
  if (tid < 16) {
    float m = st_max[0][tid];
#pragma unroll
    for (int ww = 1; ww < 8; ++ww) m = fmaxf(m, st_max[ww][tid]);
    rowmax_s[tid] = m;
  }
  __syncthreads();

  float rm[4], sm[4] = {0.f, 0.f, 0.f, 0.f};
#pragma unroll
  for (int j = 0; j < 4; ++j) rm[j] = rowmax_s[g * 4 + j];
#pragma unroll
  for (int n = 0; n < 16; ++n) {
#pragma unroll
    for (int j = 0; j < 4; ++j) {
      float e = __expf(acc[n][j] - rm[j]);
      acc[n][j] = e;
      sm[j] += e;
    }
  }
#pragma unroll
  for (int j = 0; j < 4; ++j) {
    sm[j] += __shfl_xor(sm[j], 1);
    sm[j] += __shfl_xor(sm[j], 2);
    sm[j] += __shfl_xor(sm[j], 4);
    sm[j] += __shfl_xor(sm[j], 8);
  }
  if (cl == 0) {
#pragma unroll
    for (int j = 0; j < 4; ++j) st_sum[w][g * 4 + j] = sm[j];
  }
  __syncthreads();
  if (tid < 16) {
    float s = st_sum[0][tid];
#pragma unroll
    for (int ww = 1; ww < 8; ++ww) s += st_sum[ww][tid];
    rowinv_s[tid] = 1.0f / s;
  }
  __syncthreads();

  unsigned short* Tw = (unsigned short*)Bsh + (w << 12);
  float inv[4];
#pragma unroll
  for (int j = 0; j < 4; ++j) inv[j] = rowinv_s[g * 4 + j];
#pragma unroll
  for (int n = 0; n < 16; ++n) {
#pragma unroll
    for (int j = 0; j < 4; ++j)
      Tw[(g * 4 + j) * 256 + n * 16 + cl] = f2bf(acc[n][j] * inv[j]);
  }
  __syncthreads();

  unsigned short* obase = adj + ((size_t)b * 2048 + n0) * 2048 + (w << 8);
#pragma unroll
  for (int r = 0; r < 16; ++r) {
    uint2 v = *(const uint2*)(Tw + r * 256 + lane * 4);
    *(uint2*)(obase + (size_t)r * 2048 + lane * 4) = v;
  }
}

// ---------------- phase C producers ----------------

__device__ __forceinline__ void compute_mat(const float* w, const float* xv, float* out) {
  float4 a[8];
#pragma unroll
  for (int i = 0; i < 8; ++i) a[i] = make_float4(0.f, 0.f, 0.f, 0.f);
#pragma unroll
  for (int k = 0; k < 32; ++k) {
    float xk = xv[k];
#pragma unroll
    for (int d4 = 0; d4 < 8; ++d4) {
      float4 wv = ((const float4*)(w + k * 32))[d4];
      a[d4].x += xk * wv.x; a[d4].y += xk * wv.y; a[d4].z += xk * wv.z; a[d4].w += xk * wv.w;
    }
  }
#pragma unroll
  for (int d4 = 0; d4 < 8; ++d4) {
    out[4 * d4 + 0] = a[d4].x; out[4 * d4 + 1] = a[d4].y;
    out[4 * d4 + 2] = a[d4].z; out[4 * d4 + 3] = a[d4].w;
  }
}

__device__ __forceinline__ void store32bf(unsigned short* p, const float* v) {
#pragma unroll
  for (int i = 0; i < 4; ++i) {
    uint4 u;
    u.x = (unsigned)f2bf(v[8 * i + 0]) | ((unsigned)f2bf(v[8 * i + 1]) << 16);
    u.y = (unsigned)f2bf(v[8 * i + 2]) | ((unsigned)f2bf(v[8 * i + 3]) << 16);
    u.z = (unsigned)f2bf(v[8 * i + 4]) | ((unsigned)f2bf(v[8 * i + 5]) << 16);
    u.w = (unsigned)f2bf(v[8 * i + 6]) | ((unsigned)f2bf(v[8 * i + 7]) << 16);
    ((uint4*)p)[i] = u;
  }
}

__global__ __launch_bounds__(256) void k_zb(const float* __restrict__ x,
                                            const float* __restrict__ W2,
                                            const float* __restrict__ Ws0,
                                            const float* __restrict__ Ws1,
                                            unsigned short* __restrict__ z0T,
                                            unsigned short* __restrict__ bias0,
                                            unsigned short* __restrict__ bias1) {
  __shared__ __align__(16) float w[3][1024];
  int tid = threadIdx.x;
  for (int i = tid; i < 1024; i += 256) {
    w[0][i] = W2[i]; w[1][i] = Ws0[i]; w[2][i] = Ws1[i];
  }
  __syncthreads();
  int bx = blockIdx.x;
  int b = bx / 96, r = bx % 96, t = r >> 3, mc = r & 7;
  int m = (mc << 8) + tid;
  const float4* xp = (const float4*)(x + (((size_t)(b * 2048 + m)) * 12 + t) * 32);
  float xv[32];
#pragma unroll
  for (int i = 0; i < 8; ++i) {
    float4 v = xp[i];
    xv[4 * i + 0] = v.x; xv[4 * i + 1] = v.y; xv[4 * i + 2] = v.z; xv[4 * i + 3] = v.w;
  }
  float out[32];
  compute_mat(w[0], xv, out);
  unsigned short* zp = z0T + (size_t)b * 786432 + (size_t)(t * 32) * 2048 + m;
#pragma unroll
  for (int d = 0; d < 32; ++d) zp[(size_t)d * 2048] = f2bf(out[d]);
  size_t bb = ((size_t)(b * 2048 + m)) * 384 + t * 32;
  compute_mat(w[1], xv, out);
  store32bf(bias0 + bb, out);
  compute_mat(w[2], xv, out);
  store32bf(bias1 + bb, out);
}

// ---------------- phase C: adj @ z (+bias) MFMA GEMM ----------------
// 128x192 tile, BK=64, counted-vmcnt double-buffer pipeline, 512 blocks (exactly 2/CU)

template <int OUT_F32>
__global__ __launch_bounds__(256, 2) void gemm_adj(const unsigned short* __restrict__ adj,
                                                   const unsigned short* __restrict__ Bt,
                                                   const unsigned short* __restrict__ bias,
                                                   void* __restrict__ outp) {
  const int tid = threadIdx.x;
  const int lane = tid & 63;
  const int wid = tid >> 6;
  const int wr = wid >> 1, wc = wid & 1;
  // XCD-bijective swizzle: 512 blocks = 8 XCDs x 64; each XCD owns 2 whole batches
  const int orig = blockIdx.x;
  const int wg = (orig & 7) * 64 + (orig >> 3);
  const int b = wg >> 5;
  const int w32 = wg & 31;
  const int m0 = ((w32 >> 1) & 15) << 7;
  const int c0 = (w32 & 1) * 192;

  // per buffer: A 128x64 (16KB) + B 192x64 (24KB) = 40KB; double = 80KB
  __shared__ __align__(16) unsigned char smem[81920];

  const unsigned short* aBase = adj + ((size_t)b << 22);
  const unsigned short* bBase = Bt + (size_t)b * 786432;
  // per-thread staging sources (swizzled chunk within row is pass-invariant)
  const int jx = ((tid & 7) ^ ((tid >> 3) & 7)) << 3;
  const unsigned short* gA = aBase + (size_t)(m0 + (tid >> 3)) * 2048 + jx;
  const unsigned short* gB = bBase + (size_t)(c0 + (tid >> 3)) * 2048 + jx;

  int aoff[2][4], boff[2][6];
#pragma unroll
  for (int kk = 0; kk < 2; ++kk) {
    int c = kk * 4 + (lane >> 4);
#pragma unroll
    for (int f = 0; f < 4; ++f) {
      int rA = wr * 64 + f * 16 + (lane & 15);
      aoff[kk][f] = rA * 128 + ((c ^ (rA & 7)) << 4);
    }
#pragma unroll
    for (int n = 0; n < 6; ++n) {
      int rB = wc * 96 + n * 16 + (lane & 15);
      boff[kk][n] = 16384 + rB * 128 + ((c ^ (rB & 7)) << 4);
    }
  }

  f32x4 acc[4][6] = {};

#define STAGE(BUF, KT)                                                              \
  {                                                                                 \
    _Pragma("unroll") for (int ii = 0; ii < 4; ++ii)                                \
        gload16(gA + (size_t)ii * 65536 + (KT)*64, smem + (BUF) + ii * 4096 + tid * 16); \
    _Pragma("unroll") for (int ii = 0; ii < 6; ++ii)                                \
        gload16(gB + (size_t)ii * 65536 + (KT)*64,                                  \
                smem + (BUF) + 16384 + ii * 4096 + tid * 16);                       \
  }

  // prologue: tile 0 -> buffer 0
  STAGE(0, 0);

  int cur = 0;
  for (int kt = 0; kt < 32; ++kt) {
    const int nxt = cur ^ 40960;
    if (kt < 31) {
      STAGE(nxt, kt + 1);
      asm volatile("s_waitcnt vmcnt(10)" ::: "memory");  // cur's 10 landed; nxt's 10 in flight
    } else {
      asm volatile("s_waitcnt vmcnt(0)" ::: "memory");
    }
    __builtin_amdgcn_s_barrier();
#pragma unroll
    for (int kk = 0; kk < 2; ++kk) {
      bf16x8 af[4], bfv[6];
#pragma unroll
      for (int f = 0; f < 4; ++f) af[f] = *(const bf16x8*)(smem + cur + aoff[kk][f]);
#pragma unroll
      for (int n = 0; n < 6; ++n) bfv[n] = *(const bf16x8*)(smem + cur + boff[kk][n]);
#pragma unroll
      for (int m = 0; m < 4; ++m)
#pragma unroll
        for (int n = 0; n < 6; ++n)
          acc[m][n] = __builtin_amdgcn_mfma_f32_16x16x32_bf16(af[m], bfv[n], acc[m][n], 0, 0, 0);
    }
    __builtin_amdgcn_s_barrier();  // all waves done reading cur before its overwrite lands
    cur = nxt;
  }
#undef STAGE

  const int cl = lane & 15;
  const int r4 = (lane >> 4) << 2;
  const unsigned short* bi = bias + (size_t)b * 786432;
  if (OUT_F32) {
    float* o = (float*)outp + (size_t)b * 786432;
#pragma unroll
    for (int m = 0; m < 4; ++m) {
      int row0 = m0 + wr * 64 + m * 16 + r4;
#pragma unroll
      for (int n = 0; n < 6; ++n) {
        int col = c0 + wc * 96 + n * 16 + cl;
#pragma unroll
        for (int r = 0; r < 4; ++r) {
          int row = row0 + r;
          o[(size_t)row * 384 + col] = acc[m][n][r] + bf2f(bi[(size_t)row * 384 + col]);
        }
      }
    }
  } else {
    unsigned short* o = (unsigned short*)outp + (size_t)b * 786432;
#pragma unroll
    for (int m = 0; m < 4; ++m) {
      int row0 = m0 + wr * 64 + m * 16 + r4;
#pragma unroll
      for (int n = 0; n < 6; ++n) {
        int col = c0 + wc * 96 + n * 16 + cl;
        ushort4 pk;
        pk.x = f2bf(acc[m][n][0] + bf2f(bi[(size_t)(row0 + 0) * 384 + col]));
        pk.y = f2bf(acc[m][n][1] + bf2f(bi[(size_t)(row0 + 1) * 384 + col]));
        pk.z = f2bf(acc[m][n][2] + bf2f(bi[(size_t)(row0 + 2) * 384 + col]));
        pk.w = f2bf(acc[m][n][3] + bf2f(bi[(size_t)(row0 + 3) * 384 + col]));
        *(ushort4*)(o + (size_t)col * 2048 + row0) = pk;
      }
    }
  }
}

// ---------------- launch ----------------

extern "C" void kernel_launch(void* const* d_in, const int* in_sizes, int n_in,
                              void* d_out, int out_size, void* d_ws, size_t ws_size,
                              hipStream_t stream) {
  const float* x = (const float*)d_in[0];
  const float* dis = (const float*)d_in[1];
  const float* K_S = (const float*)d_in[2];
  const float* V_S = (const float*)d_in[3];
  const float* K_T = (const float*)d_in[4];
  const float* V_T = (const float*)d_in[5];
  const float* W_Q0 = (const float*)d_in[6];
  const float* W_QS = (const float*)d_in[7];
  const float* W_QT = (const float*)d_in[8];
  const float* W2 = (const float*)d_in[9];
  const float* W_s0 = (const float*)d_in[10];
  const float* W_s1 = (const float*)d_in[11];

  char* ws = (char*)d_ws;
  float* xmn = (float*)(ws + 0);                             //     24,576 B
  float* pqs = (float*)(ws + 28672);                         //  2,097,152 B
  unsigned short* ets_bf = (unsigned short*)(ws + 2130432);  //  1,048,576 B
  unsigned short* adj = (unsigned short*)(ws + 3179008);     // 134,217,728 B
  unsigned short* z0T = (unsigned short*)(ws + 137396736);   // 25,165,824 B
  unsigned short* z1T = (unsigned short*)(ws + 162562560);   // 25,165,824 B
  unsigned short* bias0 = (unsigned short*)(ws + 187728384); // 25,165,824 B
  unsigned short* bias1 = (unsigned short*)(ws + 212894208); // 25,165,824 B

  k_xmn<<<192, 256, 0, stream>>>(x, xmn);
  k_qs<<<512, 256, 0, stream>>>(x, W_Q0, W_QS, pqs);
  k_post<<<16, 256, 0, stream>>>(pqs, xmn, W_Q0, W_QT, K_T, K_S, V_T, V_S, ets_bf);
  k_adj<<<2048, 512, 0, stream>>>(ets_bf, dis, adj);
  k_zb<<<1536, 256, 0, stream>>>(x, W2, W_s0, W_s1, z0T, bias0, bias1);
  gemm_adj<0><<<512, 256, 0, stream>>>(adj, z0T, bias0, (void*)z1T);
  gemm_adj<1><<<512, 256, 0, stream>>>(adj, z1T, bias1, d_out);
}